// Round 7
// baseline (775.252 us; speedup 1.0000x reference)
//
#include <hip/hip_runtime.h>

typedef unsigned short u16;
typedef unsigned int   u32;
typedef __bf16 bf16x8 __attribute__((ext_vector_type(8)));
typedef float  f32x4  __attribute__((ext_vector_type(4)));

// packed-weight regions (bf16 elements) in d_ws
#define OFF_W2  196608
#define OFF_W3  245760
#define OFF_TG  270336
#define OFF_TW1 335872
#define OFF_TW2 352256
#define NPACK   360448

// native f32->bf16 (RNE): compiles to v_cvt_pk_bf16_f32 (1 op) instead of 4-op manual RNE
__device__ __forceinline__ u16 f2bf(float f) {
  union { __bf16 b; u16 u; } cv;
  cv.b = (__bf16)f;
  return cv.u;
}
__device__ __forceinline__ u32 f2bf2(float lo, float hi) {
  return (u32)f2bf(lo) | ((u32)f2bf(hi) << 16);
}
__device__ __forceinline__ float bf2f(u16 s) { return __uint_as_float(((u32)s) << 16); }

union U4 { uint4 u; bf16x8 v; };
__device__ __forceinline__ bf16x8 ld_frag(const u16* p) {
  U4 t; t.u = *(const uint4*)p; return t.v;
}
__device__ __forceinline__ f32x4 mfma16(bf16x8 a, bf16x8 b, f32x4 c) {
  return __builtin_amdgcn_mfma_f32_16x16x32_bf16(a, b, c, 0, 0, 0);
}
__device__ __forceinline__ float swishf(float x) { return x / (1.f + __expf(-x)); }

// ---------------- weight repack: f32 row-major -> bf16 fragment order ----------------
// frag element (lane,i) of tile (nt,kt) = W[k][n], k = kt*32 + (lane>>4)*8 + i, n = nt*16 + (lane&15)
__global__ __launch_bounds__(256) void prep_pack(
    const float* __restrict__ eW1, const float* __restrict__ eW2,
    const float* __restrict__ eW3, const float* __restrict__ tgW1,
    const float* __restrict__ twW1, const float* __restrict__ twW2,
    u16* __restrict__ pk)
{
  int idx = blockIdx.x * 256 + threadIdx.x;
  if (idx >= NPACK) return;
  float v;
  if (idx < OFF_W2) {                 // exp_W1: [6][nt:8][kt:8][64][8]
    int i = idx & 7, lane = (idx >> 3) & 63, kt = (idx >> 9) & 7, nt = (idx >> 12) & 7, e = idx >> 15;
    int k = kt*32 + (lane>>4)*8 + i, n = nt*16 + (lane & 15);
    v = eW1[(e*256 + k)*128 + n];
  } else if (idx < OFF_W3) {          // exp_W2: [6][nt:4][kt:4][64][8]
    int j = idx - OFF_W2;
    int i = j & 7, lane = (j >> 3) & 63, kt = (j >> 9) & 3, nt = (j >> 11) & 3, e = j >> 13;
    int k = kt*32 + (lane>>4)*8 + i, n = nt*16 + (lane & 15);
    v = eW2[(e*128 + k)*64 + n];
  } else if (idx < OFF_TG) {          // exp_W3: [6][nt:4][kt:2][64][8]
    int j = idx - OFF_W3;
    int i = j & 7, lane = (j >> 3) & 63, kt = (j >> 9) & 1, nt = (j >> 10) & 3, e = j >> 12;
    int k = kt*32 + (lane>>4)*8 + i, n = nt*16 + (lane & 15);
    v = eW3[(e*64 + k)*64 + n];
  } else if (idx < OFF_TW1) {         // tg_W1: [4][nt:4][kt:8][64][8]
    int j = idx - OFF_TG;
    int i = j & 7, lane = (j >> 3) & 63, kt = (j >> 9) & 7, nt = (j >> 12) & 3, t = j >> 14;
    int k = kt*32 + (lane>>4)*8 + i, n = nt*16 + (lane & 15);
    v = tgW1[(t*256 + k)*64 + n];
  } else if (idx < OFF_TW2) {         // tw_W1: [4][nt:4][kt:2][64][8]
    int j = idx - OFF_TW1;
    int i = j & 7, lane = (j >> 3) & 63, kt = (j >> 9) & 1, nt = (j >> 10) & 3, t = j >> 12;
    int k = kt*32 + (lane>>4)*8 + i, n = nt*16 + (lane & 15);
    v = twW1[(t*64 + k)*64 + n];
  } else {                            // tw_W2: [4][nt:2][kt:2][64][8]
    int j = idx - OFF_TW2;
    int i = j & 7, lane = (j >> 3) & 63, kt = (j >> 9) & 1, nt = (j >> 10) & 1, t = j >> 11;
    int k = kt*32 + (lane>>4)*8 + i, n = nt*16 + (lane & 15);
    v = twW2[(t*64 + k)*32 + n];
  }
  pk[idx] = f2bf(v);
}

// ---------------- fused main kernel: 64 rows/block, 512 threads (8 waves), loops 4 tasks ----------------
// VGPR calibration (measured r1-r6): arch budget = 256/min_waves: min2->128, min3->84, min4->64(spills).
// Per-thread state identical to r6 (1 row/thread; 1 n-tile/wave in GEMM1) -> ~84 VGPR, no spill.
// vs r6: barriers-per-row halved (17/sub per 64 rows), per-row L2 weight traffic halved.
// LDS 77 KB -> 2 blocks/CU = 16 waves/CU (4 waves/SIMD >= min 3, consistent).
// Wave split: {tg1, GEMM3, T1} on waves 4-7; {GEMM2, T2} on waves 0-3; GEMM1 on all 8.
__global__ __launch_bounds__(512, 3) void home_main(
    const float* __restrict__ zs, const float* __restrict__ zg0, const float* __restrict__ zg1,
    const float* __restrict__ fgA, const float* __restrict__ fgB,
    const float* __restrict__ tgW2, const float* __restrict__ tgb1, const float* __restrict__ tgb2,
    const float* __restrict__ eb1, const float* __restrict__ eb2, const float* __restrict__ eb3,
    const float* __restrict__ lns, const float* __restrict__ lnb,
    const float* __restrict__ sgW, const float* __restrict__ sgb,
    const float* __restrict__ twb1, const float* __restrict__ twb2,
    const float* __restrict__ twW3, const float* __restrict__ twb3,
    const u16* __restrict__ pk, float* __restrict__ out)
{
  __shared__ __align__(16) u16   cmfrag[4*8*64*8];   // 32 KB  cm A-frags [mt4][kt8][64][8]; pre-z then gated
  __shared__ __align__(16) u16   h1frag[4*4*64*8];   // 16 KB  h1 A-frags [mt4][kt4][64][8]; alias fgBs f32[2304]
  __shared__ __align__(16) u16   h2frag[4*2*64*8];   //  8 KB  h2 A-frags ; alias aggfrag
  __shared__ __align__(16) float fbuf[64*68];        // 17 KB  gh / e_pre ; alias fgAs f32[2112], th1frag u16[4096]
  __shared__ __align__(16) float gwbuf[256];         //  1 KB  softmax gate weights [64][4]
  __shared__ __align__(16) float arrp[128];          //  0.5 KB tower partials [2][64]
  __shared__ __align__(16) float smallw[320];        //  1.25 KB tg_W2^T swizzled

  float* fgAs    = fbuf;            // [q:8][264]
  float* fgBs    = (float*)h1frag;  // [rr:8][q:8][36]
  u16*   aggfrag = h2frag;          // [mt4][kt2][64][8]
  u16*   th1frag = (u16*)fbuf;      // [mt4][kt2][64][8]

  const int tid  = threadIdx.x;
  const int lane = tid & 63;
  const int wid  = tid >> 6;       // wave 0..7
  const int r    = tid >> 3;       // row 0..63
  const int q    = tid & 7;        // eighth of the 256-d feature
  const int rowBase = blockIdx.x * 64;
  const int mt_r = r >> 4, r15 = r & 15;
  const int rl   = (lane >> 4) * 4;   // C-layout row offset
  const int l15  = lane & 15;
  const f32x4 fz = {0.f, 0.f, 0.f, 0.f};

  #pragma unroll 1
  for (int pair = 0; pair < 2; ++pair) {
    const int g = pair;
    #pragma unroll 1
    for (int sub = 0; sub < 2; ++sub) {
      const int t = pair * 2 + sub;

      // ---------- stage cm_pre (bf16) directly into cmfrag + fgA/fgB/tgW2 into LDS ----------
      {
        const float* zsrc = (q < 4)
          ? (zs + (size_t)(rowBase + r) * 128 + q * 32)
          : ((pair ? zg1 : zg0) + (size_t)(rowBase + r) * 128 + (q - 4) * 32);
        #pragma unroll
        for (int h = 0; h < 4; ++h) {
          float4 a = ((const float4*)zsrc)[2*h], b4 = ((const float4*)zsrc)[2*h+1];
          uint4 wv;
          wv.x = f2bf2(a.x, a.y);
          wv.y = f2bf2(a.z, a.w);
          wv.z = f2bf2(b4.x, b4.y);
          wv.w = f2bf2(b4.z, b4.w);
          *(uint4*)&cmfrag[((mt_r*8 + q)*64 + r15 + 16*h)*8] = wv;
        }
      }
      #pragma unroll
      for (int u = 0; u < 4; ++u) {
        int idx = tid + u*512;
        int c = idx >> 3, rr = idx & 7;
        fgAs[(c>>5)*264 + (c&31)*8 + rr] = fgA[t*2048 + idx];
      }
      #pragma unroll
      for (int u = 0; u < 4; ++u) {
        int idx = tid + u*512;
        int rr = idx >> 8, c = idx & 255;
        fgBs[rr*288 + (c>>5)*36 + (c&31)] = fgB[t*2048 + idx];
      }
      if (tid < 256) {
        int e = tid >> 6, c = tid & 63, half = c >> 5, cl = c & 31;
        smallw[(e*2 + half)*36 + cl] = tgW2[t*256 + c*4 + e];
      }
      __syncthreads();   // A

      // ---------- feature gate (in-place on cmfrag): racc = cm_pre @ fg_A, gate, repack ----------
      {
        u32 zz[16];
        #pragma unroll
        for (int h = 0; h < 4; ++h) {
          uint4 wv = *(const uint4*)&cmfrag[((mt_r*8 + q)*64 + r15 + 16*h)*8];
          zz[4*h] = wv.x; zz[4*h+1] = wv.y; zz[4*h+2] = wv.z; zz[4*h+3] = wv.w;
        }
        float acc[8];
        #pragma unroll
        for (int rr = 0; rr < 8; ++rr) acc[rr] = 0.f;
        const float* Ap = fgAs + q*264;
        #pragma unroll
        for (int jf = 0; jf < 8; ++jf) {
          u32 p0 = zz[2*jf], p1 = zz[2*jf+1];
          float zc[4] = { bf2f((u16)p0), bf2f((u16)(p0>>16)), bf2f((u16)p1), bf2f((u16)(p1>>16)) };
          #pragma unroll
          for (int u = 0; u < 4; ++u) {
            const float4* ar = (const float4*)(Ap + (jf*4 + u)*8);
            float4 lo = ar[0], hi = ar[1];
            acc[0] += zc[u]*lo.x; acc[1] += zc[u]*lo.y; acc[2] += zc[u]*lo.z; acc[3] += zc[u]*lo.w;
            acc[4] += zc[u]*hi.x; acc[5] += zc[u]*hi.y; acc[6] += zc[u]*hi.z; acc[7] += zc[u]*hi.w;
          }
        }
        #pragma unroll
        for (int rr = 0; rr < 8; ++rr) {
          acc[rr] += __shfl_xor(acc[rr], 1);
          acc[rr] += __shfl_xor(acc[rr], 2);
          acc[rr] += __shfl_xor(acc[rr], 4);
        }
        #pragma unroll
        for (int h = 0; h < 4; ++h) {
          u16 pk8[8];
          #pragma unroll
          for (int half = 0; half < 2; ++half) {
            const float* bp = fgBs + q*36 + h*8 + half*4;
            float l0=0.f, l1=0.f, l2=0.f, l3=0.f;
            #pragma unroll
            for (int rr = 0; rr < 8; ++rr) {
              float4 b4 = *(const float4*)(bp + rr*288);
              l0 += acc[rr]*b4.x; l1 += acc[rr]*b4.y; l2 += acc[rr]*b4.z; l3 += acc[rr]*b4.w;
            }
            int zi = h*4 + half*2;
            u32 p0 = zz[zi], p1 = zz[zi+1];
            float zv[4] = { bf2f((u16)p0), bf2f((u16)(p0>>16)), bf2f((u16)p1), bf2f((u16)(p1>>16)) };
            float lg[4] = { l0, l1, l2, l3 };
            #pragma unroll
            for (int u = 0; u < 4; ++u) {
              float gate = 2.f / (1.f + __expf(-lg[u]));
              pk8[half*4 + u] = f2bf(zv[u] * gate);
            }
          }
          uint4 wv;
          wv.x = (u32)pk8[0] | ((u32)pk8[1] << 16);
          wv.y = (u32)pk8[2] | ((u32)pk8[3] << 16);
          wv.z = (u32)pk8[4] | ((u32)pk8[5] << 16);
          wv.w = (u32)pk8[6] | ((u32)pk8[7] << 16);
          *(uint4*)&cmfrag[((mt_r*8 + q)*64 + r15 + 16*h)*8] = wv;
        }
      }
      __syncthreads();   // B

      // ---------- task gate layer1 (waves 4-7): gh = swish(cm @ tg_W1 + b) ----------
      if (wid >= 4) {
        f32x4 accg[4] = { fz, fz, fz, fz };
        const u16* wp = pk + OFF_TG + ((t*4 + (wid-4))*8)*512 + lane*8;
        #pragma unroll
        for (int kt = 0; kt < 8; ++kt) {
          bf16x8 bfr = ld_frag(wp + kt*512);
          #pragma unroll
          for (int mt = 0; mt < 4; ++mt) {
            bf16x8 afr = ld_frag(&cmfrag[((mt*8 + kt)*64 + lane)*8]);
            accg[mt] = mfma16(afr, bfr, accg[mt]);
          }
        }
        int colg = (wid-4)*16 + l15;
        float bias = tgb1[t*64 + colg];
        #pragma unroll
        for (int mt = 0; mt < 4; ++mt)
          #pragma unroll
          for (int rr = 0; rr < 4; ++rr)
            fbuf[(mt*16 + rl + rr)*68 + colg] = swishf(accg[mt][rr] + bias);
      }
      __syncthreads();   // C

      // ---------- task gate layer2 + softmax (lanes q,q+4 split the 64-dim dot) ----------
      {
        int e = q & 3, half = q >> 2;
        float part = 0.f;
        #pragma unroll
        for (int cj = 0; cj < 8; ++cj) {
          float4 g4 = *(const float4*)&fbuf[r*68 + half*32 + cj*4];
          float4 w4 = *(const float4*)&smallw[(e*2 + half)*36 + cj*4];
          part += g4.x*w4.x + g4.y*w4.y + g4.z*w4.z + g4.w*w4.w;
        }
        part += __shfl_xor(part, 4);
        float logit = part + tgb2[t*4 + e];
        float mx = fmaxf(logit, __shfl_xor(logit, 1));
        mx = fmaxf(mx, __shfl_xor(mx, 2));
        float ex = __expf(logit - mx);
        float sm = ex + __shfl_xor(ex, 1);
        sm += __shfl_xor(sm, 2);
        if (q < 4) gwbuf[r*4 + q] = ex / sm;
      }
      // NO barrier: gwbuf's first reader (LN, el=0) is >=3 barriers (E1,E2,E3) downstream.

      // ---------- expert loop ----------
      float agg[8];
      #pragma unroll
      for (int c = 0; c < 8; ++c) agg[c] = 0.f;

      #pragma unroll 1
      for (int el = 0; el < 4; ++el) {
        const int ei = (el < 2) ? el : (el + 2*g);

        // GEMM1: cm(64x256) @ W1(256x128); all 8 waves, wave w owns n-tile w
        f32x4 acc1[4] = { fz, fz, fz, fz };
        {
          const u16* w1p = pk + ((ei*8 + wid)*8)*512 + lane*8;
          #pragma unroll
          for (int kt = 0; kt < 8; ++kt) {
            bf16x8 b0 = ld_frag(w1p + kt*512);
            #pragma unroll
            for (int mt = 0; mt < 4; ++mt) {
              bf16x8 a = ld_frag(&cmfrag[((mt*8 + kt)*64 + lane)*8]);
              acc1[mt] = mfma16(a, b0, acc1[mt]);
            }
          }
        }
        {
          int col = wid*16 + l15;
          float bias = eb1[ei*128 + col];
          int kt2 = col >> 5, h2 = (col >> 3) & 3, i2 = col & 7;
          #pragma unroll
          for (int mt = 0; mt < 4; ++mt)
            #pragma unroll
            for (int rr = 0; rr < 4; ++rr)
              h1frag[((mt*4 + kt2)*64 + rl + rr + 16*h2)*8 + i2] = f2bf(swishf(acc1[mt][rr] + bias));
        }
        __syncthreads();  // E1

        // GEMM2 (waves 0-3): h1(64x128) @ W2(128x64)
        if (wid < 4) {
          f32x4 acc2[4] = { fz, fz, fz, fz };
          const u16* w2p = pk + OFF_W2 + ((ei*4 + wid)*4)*512 + lane*8;
          #pragma unroll
          for (int kt = 0; kt < 4; ++kt) {
            bf16x8 b0 = ld_frag(w2p + kt*512);
            #pragma unroll
            for (int mt = 0; mt < 4; ++mt) {
              bf16x8 a = ld_frag(&h1frag[((mt*4 + kt)*64 + lane)*8]);
              acc2[mt] = mfma16(a, b0, acc2[mt]);
            }
          }
          int col = wid*16 + l15;
          float bias = eb2[ei*64 + col];
          int kt2 = col >> 5, h2 = (col >> 3) & 3, i2 = col & 7;
          #pragma unroll
          for (int mt = 0; mt < 4; ++mt)
            #pragma unroll
            for (int rr = 0; rr < 4; ++rr)
              h2frag[((mt*2 + kt2)*64 + rl + rr + 16*h2)*8 + i2] = f2bf(swishf(acc2[mt][rr] + bias));
        }
        __syncthreads();  // E2

        // GEMM3 (waves 4-7): h2(64x64) @ W3(64x64) -> e_pre into fbuf
        if (wid >= 4) {
          f32x4 acc3[4] = { fz, fz, fz, fz };
          const u16* w3p = pk + OFF_W3 + ((ei*4 + (wid-4))*2)*512 + lane*8;
          #pragma unroll
          for (int kt = 0; kt < 2; ++kt) {
            bf16x8 b0 = ld_frag(w3p + kt*512);
            #pragma unroll
            for (int mt = 0; mt < 4; ++mt) {
              bf16x8 a = ld_frag(&h2frag[((mt*2 + kt)*64 + lane)*8]);
              acc3[mt] = mfma16(a, b0, acc3[mt]);
            }
          }
          int col = (wid-4)*16 + l15;
          float bias = eb3[ei*64 + col];
          #pragma unroll
          for (int mt = 0; mt < 4; ++mt)
            #pragma unroll
            for (int rr = 0; rr < 4; ++rr)
              fbuf[(mt*16 + rl + rr)*68 + col] = acc3[mt][rr] + bias;
        }
        __syncthreads();  // E3

        // LayerNorm + self-gate diag + weighted aggregate (thread (r,q): 8 cols of row r)
        {
          float v[8];
          float4 fa = *(const float4*)&fbuf[r*68 + q*8];
          float4 fb = *(const float4*)&fbuf[r*68 + q*8 + 4];
          v[0]=fa.x; v[1]=fa.y; v[2]=fa.z; v[3]=fa.w;
          v[4]=fb.x; v[5]=fb.y; v[6]=fb.z; v[7]=fb.w;
          float s1 = 0.f;
          #pragma unroll
          for (int c = 0; c < 8; ++c) s1 += v[c];
          s1 += __shfl_xor(s1, 1); s1 += __shfl_xor(s1, 2); s1 += __shfl_xor(s1, 4);
          float mu = s1 * (1.f/64.f);
          float s2 = 0.f;
          #pragma unroll
          for (int c = 0; c < 8; ++c) { float d = v[c] - mu; s2 += d*d; }
          s2 += __shfl_xor(s2, 1); s2 += __shfl_xor(s2, 2); s2 += __shfl_xor(s2, 4);
          float rs = rsqrtf(s2 * (1.f/64.f) + 1e-5f);
          const float* lsp = lns + ei*64 + q*8;
          const float* lbp = lnb + ei*64 + q*8;
          const float* sgp = sgW + (t*64 + q*8)*4 + el;
          float swp = 0.f;
          #pragma unroll
          for (int c = 0; c < 8; ++c) {
            float eh = (v[c] - mu) * rs * lsp[c] + lbp[c];
            v[c] = eh;
            swp += eh * sgp[c*4];
          }
          swp += __shfl_xor(swp, 1); swp += __shfl_xor(swp, 2); swp += __shfl_xor(swp, 4);
          swp += sgb[t*4 + el];
          float fac = swp * gwbuf[r*4 + el];
          #pragma unroll
          for (int c = 0; c < 8; ++c) agg[c] += v[c] * fac;
        }
        // no trailing barrier: next GEMM1 writes h1frag after E1-equivalent ordering via loop barrier E1.
      }  // expert loop

      // ---------- tower via MFMA: agg(64x64) @ W1 -> swish -> @ W2(64x32) -> swish -> @ w3 ----------
      {
        uint4 wv;
        wv.x = f2bf2(agg[0], agg[1]);
        wv.y = f2bf2(agg[2], agg[3]);
        wv.z = f2bf2(agg[4], agg[5]);
        wv.w = f2bf2(agg[6], agg[7]);
        *(uint4*)&aggfrag[((mt_r*2 + (q>>2))*64 + r15 + 16*(q&3)) * 8] = wv;
      }
      __syncthreads();  // F

      // T1 (waves 4-7): n-tile wid-4 of 64
      if (wid >= 4) {
        f32x4 at1[4] = { fz, fz, fz, fz };
        const u16* tw1p = pk + OFF_TW1 + ((t*4 + (wid-4))*2)*512 + lane*8;
        #pragma unroll
        for (int kt = 0; kt < 2; ++kt) {
          bf16x8 b0 = ld_frag(tw1p + kt*512);
          #pragma unroll
          for (int mt = 0; mt < 4; ++mt) {
            bf16x8 a = ld_frag(&aggfrag[((mt*2 + kt)*64 + lane)*8]);
            at1[mt] = mfma16(a, b0, at1[mt]);
          }
        }
        int colT = (wid-4)*16 + l15;
        float bias = twb1[t*64 + colT];
        int ktT = colT >> 5, hT = (colT >> 3) & 3, iT = colT & 7;
        #pragma unroll
        for (int mt = 0; mt < 4; ++mt)
          #pragma unroll
          for (int rr = 0; rr < 4; ++rr)
            th1frag[((mt*2 + ktT)*64 + rl + rr + 16*hT)*8 + iT] = f2bf(swishf(at1[mt][rr] + bias));
      }
      __syncthreads();  // G

      // T2 (waves 0-1): the two 16-col tiles of 32
      if (wid < 2) {
        f32x4 at2[4] = { fz, fz, fz, fz };
        const u16* tw2p = pk + OFF_TW2 + ((t*2 + wid)*2)*512 + lane*8;
        #pragma unroll
        for (int kt = 0; kt < 2; ++kt) {
          bf16x8 b0 = ld_frag(tw2p + kt*512);
          #pragma unroll
          for (int mt = 0; mt < 4; ++mt) {
            bf16x8 a = ld_frag(&th1frag[((mt*2 + kt)*64 + lane)*8]);
            at2[mt] = mfma16(a, b0, at2[mt]);
          }
        }
        int colU = wid*16 + l15;
        float b2  = twb2[t*32 + colU];
        float w3v = twW3[t*32 + colU];
        float px[16];
        #pragma unroll
        for (int mt = 0; mt < 4; ++mt)
          #pragma unroll
          for (int rr = 0; rr < 4; ++rr)
            px[mt*4 + rr] = swishf(at2[mt][rr] + b2) * w3v;
        #pragma unroll
        for (int k = 0; k < 16; ++k) {
          px[k] += __shfl_xor(px[k], 1);
          px[k] += __shfl_xor(px[k], 2);
          px[k] += __shfl_xor(px[k], 4);
          px[k] += __shfl_xor(px[k], 8);
        }
        if (l15 == 0) {
          #pragma unroll
          for (int mt = 0; mt < 4; ++mt)
            #pragma unroll
            for (int rr = 0; rr < 4; ++rr)
              arrp[wid*64 + mt*16 + rl + rr] = px[mt*4 + rr];
        }
      }
      __syncthreads();  // H

      if (tid < 64) {
        float x = arrp[tid] + arrp[64 + tid] + twb3[t];
        out[(size_t)(rowBase + tid)*4 + t] = 1.f / (1.f + __expf(-x));
      }
      // NO trailing barrier: next sub's staging targets cmfrag (last read pre-E1 of el3),
      // fgAs/th1frag region (last read T2 pre-H), fgBs/h1frag (last read pre-E2 of el3),
      // smallw (last read softmax) - all ordered by H. arrp is read-only here and its next
      // writer (next sub T2) is beyond many barriers.
    }
  }
}

extern "C" void kernel_launch(void* const* d_in, const int* in_sizes, int n_in,
                              void* d_out, int out_size, void* d_ws, size_t ws_size,
                              hipStream_t stream)
{
  (void)in_sizes; (void)n_in; (void)out_size; (void)ws_size;
  const float* zs   = (const float*)d_in[0];
  const float* zg0  = (const float*)d_in[1];
  const float* zg1  = (const float*)d_in[2];
  // d_in[3] = v : unused by the reference
  const float* eW1  = (const float*)d_in[4];
  const float* eb1  = (const float*)d_in[5];
  const float* eW2  = (const float*)d_in[6];
  const float* eb2  = (const float*)d_in[7];
  const float* eW3  = (const float*)d_in[8];
  const float* eb3  = (const float*)d_in[9];
  const float* lns  = (const float*)d_in[10];
  const float* lnb  = (const float*)d_in[11];
  const float* fgA  = (const float*)d_in[12];
  const float* fgB  = (const float*)d_in[13];
  const float* tgW1 = (const float*)d_in[14];
  const float* tgb1 = (const float*)d_in[15];
  const float* tgW2 = (const float*)d_in[16];
  const float* tgb2 = (const float*)d_in[17];
  const float* sgW  = (const float*)d_in[18];
  const float* sgb  = (const float*)d_in[19];
  const float* twW1 = (const float*)d_in[20];
  const float* twb1 = (const float*)d_in[21];
  const float* twW2 = (const float*)d_in[22];
  const float* twb2 = (const float*)d_in[23];
  const float* twW3 = (const float*)d_in[24];
  const float* twb3 = (const float*)d_in[25];

  u16* pkw = (u16*)d_ws;          // needs 720896 B
  float* outp = (float*)d_out;

  prep_pack<<<(NPACK + 255)/256, 256, 0, stream>>>(eW1, eW2, eW3, tgW1, twW1, twW2, pkw);
  home_main<<<65536/64, 512, 0, stream>>>(zs, zg0, zg1, fgA, fgB, tgW2, tgb1, tgb2,
      eb1, eb2, eb3, lns, lnb, sgW, sgb, twb1, twb2, twW3, twb3,
      pkw, outp);
}

// Round 8
// 418.565 us; speedup vs baseline: 1.8522x; 1.8522x over previous
//
#include <hip/hip_runtime.h>

typedef unsigned short u16;
typedef unsigned int   u32;
typedef __bf16 bf16x8 __attribute__((ext_vector_type(8)));
typedef float  f32x4  __attribute__((ext_vector_type(4)));

// packed-weight regions (bf16 elements) in d_ws
#define OFF_W2  196608
#define OFF_W3  245760
#define OFF_TG  270336
#define OFF_TW1 335872
#define OFF_TW2 352256
#define OFF_FGA 360448
#define OFF_FGB 376832
#define NPACK   409600

// native f32->bf16 (RNE): v_cvt_pk_bf16_f32
__device__ __forceinline__ u16 f2bf(float f) {
  union { __bf16 b; u16 u; } cv;
  cv.b = (__bf16)f;
  return cv.u;
}
__device__ __forceinline__ u32 f2bf2(float lo, float hi) {
  return (u32)f2bf(lo) | ((u32)f2bf(hi) << 16);
}
__device__ __forceinline__ float bf2f(u16 s) { return __uint_as_float(((u32)s) << 16); }
__device__ __forceinline__ float bflo(u32 p) { return __uint_as_float(p << 16); }
__device__ __forceinline__ float bfhi(u32 p) { return __uint_as_float(p & 0xffff0000u); }

union U4 { uint4 u; bf16x8 v; };
__device__ __forceinline__ bf16x8 ld_frag(const u16* p) {
  U4 t; t.u = *(const uint4*)p; return t.v;
}
__device__ __forceinline__ f32x4 mfma16(bf16x8 a, bf16x8 b, f32x4 c) {
  return __builtin_amdgcn_mfma_f32_16x16x32_bf16(a, b, c, 0, 0, 0);
}
__device__ __forceinline__ float swishf(float x) { return x / (1.f + __expf(-x)); }

// ---------------- weight repack: f32 row-major -> bf16 fragment order ----------------
// frag element (lane,i) of tile (nt,kt) = W[k][n], k = kt*32 + (lane>>4)*8 + i, n = nt*16 + (lane&15)
__global__ __launch_bounds__(256) void prep_pack(
    const float* __restrict__ eW1, const float* __restrict__ eW2,
    const float* __restrict__ eW3, const float* __restrict__ tgW1,
    const float* __restrict__ twW1, const float* __restrict__ twW2,
    const float* __restrict__ fgA, const float* __restrict__ fgB,
    u16* __restrict__ pk)
{
  int idx = blockIdx.x * 256 + threadIdx.x;
  if (idx >= NPACK) return;
  float v;
  if (idx < OFF_W2) {                 // exp_W1: [6][nt:8][kt:8][64][8]
    int i = idx & 7, lane = (idx >> 3) & 63, kt = (idx >> 9) & 7, nt = (idx >> 12) & 7, e = idx >> 15;
    int k = kt*32 + (lane>>4)*8 + i, n = nt*16 + (lane & 15);
    v = eW1[(e*256 + k)*128 + n];
  } else if (idx < OFF_W3) {          // exp_W2: [6][nt:4][kt:4][64][8]
    int j = idx - OFF_W2;
    int i = j & 7, lane = (j >> 3) & 63, kt = (j >> 9) & 3, nt = (j >> 11) & 3, e = j >> 13;
    int k = kt*32 + (lane>>4)*8 + i, n = nt*16 + (lane & 15);
    v = eW2[(e*128 + k)*64 + n];
  } else if (idx < OFF_TG) {          // exp_W3: [6][nt:4][kt:2][64][8]
    int j = idx - OFF_W3;
    int i = j & 7, lane = (j >> 3) & 63, kt = (j >> 9) & 1, nt = (j >> 10) & 3, e = j >> 12;
    int k = kt*32 + (lane>>4)*8 + i, n = nt*16 + (lane & 15);
    v = eW3[(e*64 + k)*64 + n];
  } else if (idx < OFF_TW1) {         // tg_W1: [4][nt:4][kt:8][64][8]
    int j = idx - OFF_TG;
    int i = j & 7, lane = (j >> 3) & 63, kt = (j >> 9) & 7, nt = (j >> 12) & 3, t = j >> 14;
    int k = kt*32 + (lane>>4)*8 + i, n = nt*16 + (lane & 15);
    v = tgW1[(t*256 + k)*64 + n];
  } else if (idx < OFF_TW2) {         // tw_W1: [4][nt:4][kt:2][64][8]
    int j = idx - OFF_TW1;
    int i = j & 7, lane = (j >> 3) & 63, kt = (j >> 9) & 1, nt = (j >> 10) & 3, t = j >> 12;
    int k = kt*32 + (lane>>4)*8 + i, n = nt*16 + (lane & 15);
    v = twW1[(t*64 + k)*64 + n];
  } else if (idx < OFF_FGA) {         // tw_W2: [4][nt:2][kt:2][64][8]
    int j = idx - OFF_TW2;
    int i = j & 7, lane = (j >> 3) & 63, kt = (j >> 9) & 1, nt = (j >> 10) & 1, t = j >> 11;
    int k = kt*32 + (lane>>4)*8 + i, n = nt*16 + (lane & 15);
    v = twW2[(t*64 + k)*32 + n];
  } else if (idx < OFF_FGB) {         // fgA^T A-frags: [4][kt:8][64][8]; A[m][k]=fgA[k][m], m<8 else 0
    int j = idx - OFF_FGA;
    int i = j & 7, lane = (j >> 3) & 63, kt = (j >> 9) & 7, t = j >> 12;
    int m = lane & 15, k = kt*32 + (lane>>4)*8 + i;
    v = (m < 8) ? fgA[(t*256 + k)*8 + m] : 0.f;
  } else {                            // fgB^T A-frags: [4][mtile:16][64][8]; A[m][kr]=fgB[kr][m], kr<8 else 0
    int j = idx - OFF_FGB;
    int i = j & 7, lane = (j >> 3) & 63, mtl = (j >> 9) & 15, t = j >> 13;
    int m = mtl*16 + (lane & 15), kr = (lane>>4)*8 + i;
    v = (kr < 8) ? fgB[t*2048 + kr*256 + m] : 0.f;
  }
  pk[idx] = f2bf(v);
}

// ---------------- fused main kernel: 32 rows/block, loops 4 tasks ----------------
// r6-proven shape: 256 threads, launch_bounds(256,3) -> 84 arch VGPR, no spill, LDS ~40 KB.
// (r5/r7 lesson: 64-row / 512-thread variants re-trigger spills; do not revisit.)
// This round: feature gate on MFMA pipe via transpose trick (A-frag of X == B-frag of X^T):
//   accT(8x32)=fgA^T@cm^T (waves 0-1), logitsT(256x32)=fgB^T@accT (all waves, K=32 zero-padded),
//   gate=2sig stored bf16 [32][264], applied in-place on cmfrag. Removes ~512 scalar FMAs/thread/sub.
__global__ __launch_bounds__(256, 3) void home_main(
    const float* __restrict__ zs, const float* __restrict__ zg0, const float* __restrict__ zg1,
    const float* __restrict__ tgW2, const float* __restrict__ tgb1, const float* __restrict__ tgb2,
    const float* __restrict__ eb1, const float* __restrict__ eb2, const float* __restrict__ eb3,
    const float* __restrict__ lns, const float* __restrict__ lnb,
    const float* __restrict__ sgW, const float* __restrict__ sgb,
    const float* __restrict__ twb1, const float* __restrict__ twb2,
    const float* __restrict__ twW3, const float* __restrict__ twb3,
    const u16* __restrict__ pk, float* __restrict__ out)
{
  __shared__ __align__(16) u16   cmfrag[2*8*64*8];   // 16384 B  cm A-frags [mt2][kt8][64][8]; pre-z then gated
  __shared__ __align__(16) char  region2[22528];     // gemm: h1frag|h2frag|fbuf  ||  gate: accT|gateT
  __shared__ __align__(16) float gwbuf[128];         //  gate weights ; alias tower partials
  __shared__ __align__(16) float smallw[320];        //  tg_W2^T swizzled

  u16*   h1frag = (u16*)region2;                // 9216 B (4608 u16) [mt2][kt4][64][8]
  u16*   h2frag = (u16*)(region2 + 9216);       // 4096 B [mt2][kt2][64][8]
  float* fbuf   = (float*)(region2 + 13312);    // 9216 B [32][72]
  float* accT   = (float*)region2;              // [8][34] f32 = 1088 B   (gate phase)
  u16*   gateT  = (u16*)(region2 + 1280);       // [32][264] bf16 = 16896 B (gate phase)
  u16*   aggfrag = h2frag;                      // [mt2][kt2][64][8]
  u16*   th1frag = (u16*)fbuf;                  // [mt2][kt2][64][8]
  float* arrp    = gwbuf;                       // [2][32] tower partials

  const int tid  = threadIdx.x;
  const int lane = tid & 63;
  const int wid  = tid >> 6;       // wave 0..3
  const int r    = tid >> 3;       // row 0..31
  const int q    = tid & 7;        // eighth of the 256-d feature
  const int rowBase = blockIdx.x * 32;
  const int mt_r = r >> 4, r15 = r & 15;
  const int rl   = (lane >> 4) * 4;   // C-layout row offset
  const int l15  = lane & 15;
  const f32x4 fz = {0.f, 0.f, 0.f, 0.f};

  #pragma unroll 1
  for (int pair = 0; pair < 2; ++pair) {
    const int g = pair;
    #pragma unroll 1
    for (int sub = 0; sub < 2; ++sub) {
      const int t = pair * 2 + sub;

      // ---------- stage cm_pre (bf16) directly into cmfrag + tgW2 into LDS ----------
      {
        const float* zsrc = (q < 4)
          ? (zs + (size_t)(rowBase + r) * 128 + q * 32)
          : ((pair ? zg1 : zg0) + (size_t)(rowBase + r) * 128 + (q - 4) * 32);
        #pragma unroll
        for (int h = 0; h < 4; ++h) {
          float4 a = ((const float4*)zsrc)[2*h], b4 = ((const float4*)zsrc)[2*h+1];
          uint4 wv;
          wv.x = f2bf2(a.x, a.y);
          wv.y = f2bf2(a.z, a.w);
          wv.z = f2bf2(b4.x, b4.y);
          wv.w = f2bf2(b4.z, b4.w);
          *(uint4*)&cmfrag[((mt_r*8 + q)*64 + r15 + 16*h)*8] = wv;
        }
      }
      {
        int e = tid >> 6, c = tid & 63, half = c >> 5, cl = c & 31;
        smallw[(e*2 + half)*36 + cl] = tgW2[t*256 + c*4 + e];
      }
      __syncthreads();   // A

      // ---------- gate step 1 (waves 0,1): accT(8x32) = fgA^T @ cm_pre^T ----------
      if (wid < 2) {
        f32x4 d1 = fz;
        const u16* ap = pk + OFF_FGA + (t*8)*512 + lane*8;
        #pragma unroll
        for (int kt = 0; kt < 8; ++kt) {
          bf16x8 af = ld_frag(ap + kt*512);
          bf16x8 bf = ld_frag(&cmfrag[((wid*8 + kt)*64 + lane)*8]);
          d1 = mfma16(af, bf, d1);
        }
        if (rl < 8) {      // ranks 0-7 live in lane groups 0,1
          #pragma unroll
          for (int rr = 0; rr < 4; ++rr)
            accT[(rl + rr)*34 + wid*16 + l15] = d1[rr];
        }
      }
      __syncthreads();   // A2

      // ---------- gate step 2 (all waves): logitsT = fgB^T @ accT ; gate = 2*sigmoid -> gateT ----------
      {
        // build B-frags (K=32, only k<8 nonzero -> lane group 0 holds data)
        U4 b0u, b1u;
        if (lane < 16) {
          float v0[8], v1[8];
          #pragma unroll
          for (int i = 0; i < 8; ++i) {
            v0[i] = accT[i*34 + l15];
            v1[i] = accT[i*34 + 16 + l15];
          }
          b0u.u.x = f2bf2(v0[0], v0[1]); b0u.u.y = f2bf2(v0[2], v0[3]);
          b0u.u.z = f2bf2(v0[4], v0[5]); b0u.u.w = f2bf2(v0[6], v0[7]);
          b1u.u.x = f2bf2(v1[0], v1[1]); b1u.u.y = f2bf2(v1[2], v1[3]);
          b1u.u.z = f2bf2(v1[4], v1[5]); b1u.u.w = f2bf2(v1[6], v1[7]);
        } else {
          b0u.u = make_uint4(0, 0, 0, 0);
          b1u.u = make_uint4(0, 0, 0, 0);
        }
        #pragma unroll
        for (int mt4 = 0; mt4 < 4; ++mt4) {
          int mtile = wid*4 + mt4;
          bf16x8 af = ld_frag(pk + OFF_FGB + (t*16 + mtile)*512 + lane*8);
          f32x4 d0 = mfma16(af, b0u.v, fz);
          f32x4 d1 = mfma16(af, b1u.v, fz);
          int fbase = mtile*16 + rl;
          {
            float g0 = 2.f / (1.f + __expf(-d0[0]));
            float g1 = 2.f / (1.f + __expf(-d0[1]));
            float g2 = 2.f / (1.f + __expf(-d0[2]));
            float g3 = 2.f / (1.f + __expf(-d0[3]));
            int rowc = l15;
            *(u32*)&gateT[rowc*264 + fbase]     = f2bf2(g0, g1);
            *(u32*)&gateT[rowc*264 + fbase + 2] = f2bf2(g2, g3);
          }
          {
            float g0 = 2.f / (1.f + __expf(-d1[0]));
            float g1 = 2.f / (1.f + __expf(-d1[1]));
            float g2 = 2.f / (1.f + __expf(-d1[2]));
            float g3 = 2.f / (1.f + __expf(-d1[3]));
            int rowc = 16 + l15;
            *(u32*)&gateT[rowc*264 + fbase]     = f2bf2(g0, g1);
            *(u32*)&gateT[rowc*264 + fbase + 2] = f2bf2(g2, g3);
          }
        }
      }
      __syncthreads();   // A3

      // ---------- gate apply (in-place on cmfrag); thread (r,q) owns row r, features q*32.. ----------
      {
        const int gbase = r*264 + q*32;
        #pragma unroll
        for (int h = 0; h < 4; ++h) {
          u16* cp = &cmfrag[((mt_r*8 + q)*64 + r15 + 16*h)*8];
          uint4 zv = *(const uint4*)cp;
          uint4 gv = *(const uint4*)&gateT[gbase + h*8];
          uint4 wv;
          wv.x = f2bf2(bflo(zv.x)*bflo(gv.x), bfhi(zv.x)*bfhi(gv.x));
          wv.y = f2bf2(bflo(zv.y)*bflo(gv.y), bfhi(zv.y)*bfhi(gv.y));
          wv.z = f2bf2(bflo(zv.z)*bflo(gv.z), bfhi(zv.z)*bfhi(gv.z));
          wv.w = f2bf2(bflo(zv.w)*bflo(gv.w), bfhi(zv.w)*bfhi(gv.w));
          *(uint4*)cp = wv;
        }
      }
      __syncthreads();   // B

      // ---------- task gate layer1: gh = swish(cm @ tg_W1 + b); wave w owns n-tile w ----------
      {
        f32x4 accg[2] = { fz, fz };
        const u16* wp = pk + OFF_TG + ((t*4 + wid)*8)*512 + lane*8;
        #pragma unroll
        for (int kt = 0; kt < 8; ++kt) {
          bf16x8 bfr = ld_frag(wp + kt*512);
          #pragma unroll
          for (int mt = 0; mt < 2; ++mt) {
            bf16x8 afr = ld_frag(&cmfrag[((mt*8 + kt)*64 + lane)*8]);
            accg[mt] = mfma16(afr, bfr, accg[mt]);
          }
        }
        int colg = wid*16 + l15;
        float bias = tgb1[t*64 + colg];
        #pragma unroll
        for (int mt = 0; mt < 2; ++mt)
          #pragma unroll
          for (int rr = 0; rr < 4; ++rr)
            fbuf[(mt*16 + rl + rr)*72 + colg] = swishf(accg[mt][rr] + bias);
      }
      __syncthreads();   // C

      // ---------- task gate layer2 + softmax (lanes q,q+4 split the 64-dim dot) ----------
      {
        int e = q & 3, half = q >> 2;
        float part = 0.f;
        #pragma unroll
        for (int cj = 0; cj < 8; ++cj) {
          float4 g4 = *(const float4*)&fbuf[r*72 + half*32 + cj*4];
          float4 w4 = *(const float4*)&smallw[(e*2 + half)*36 + cj*4];
          part += g4.x*w4.x + g4.y*w4.y + g4.z*w4.z + g4.w*w4.w;
        }
        part += __shfl_xor(part, 4);
        float logit = part + tgb2[t*4 + e];
        float mx = fmaxf(logit, __shfl_xor(logit, 1));
        mx = fmaxf(mx, __shfl_xor(mx, 2));
        float ex = __expf(logit - mx);
        float sm = ex + __shfl_xor(ex, 1);
        sm += __shfl_xor(sm, 2);
        if (q < 4) gwbuf[r*4 + q] = ex / sm;
      }
      // NO barrier: gwbuf's first reader (LN, el=0) is 3 barriers (E1,E2,E3) downstream;
      // GEMM1 writes h1frag (gateT/accT dead since barrier B).

      // ---------- expert loop ----------
      float agg[8];
      #pragma unroll
      for (int c = 0; c < 8; ++c) agg[c] = 0.f;

      #pragma unroll 1
      for (int el = 0; el < 4; ++el) {
        const int ei = (el < 2) ? el : (el + 2*g);

        // GEMM1: cm(32x256) @ W1(256x128); wave owns n-tiles 2w,2w+1
        f32x4 acc1[2][2];
        #pragma unroll
        for (int mt = 0; mt < 2; ++mt) { acc1[mt][0] = fz; acc1[mt][1] = fz; }
        {
          const u16* w1p = pk + ((ei*8 + 2*wid)*8)*512 + lane*8;
          #pragma unroll
          for (int kt = 0; kt < 8; ++kt) {
            bf16x8 b0 = ld_frag(w1p + kt*512);
            bf16x8 b1 = ld_frag(w1p + 4096 + kt*512);
            #pragma unroll
            for (int mt = 0; mt < 2; ++mt) {
              bf16x8 a = ld_frag(&cmfrag[((mt*8 + kt)*64 + lane)*8]);
              acc1[mt][0] = mfma16(a, b0, acc1[mt][0]);
              acc1[mt][1] = mfma16(a, b1, acc1[mt][1]);
            }
          }
        }
        #pragma unroll
        for (int nn = 0; nn < 2; ++nn) {
          int col = (2*wid + nn)*16 + l15;
          float bias = eb1[ei*128 + col];
          int kt2 = col >> 5, h2 = (col >> 3) & 3, i2 = col & 7;
          #pragma unroll
          for (int mt = 0; mt < 2; ++mt)
            #pragma unroll
            for (int rr = 0; rr < 4; ++rr)
              h1frag[((mt*4 + kt2)*64 + rl + rr + 16*h2)*8 + i2] = f2bf(swishf(acc1[mt][nn][rr] + bias));
        }
        __syncthreads();  // E1

        // GEMM2: h1(32x128) @ W2(128x64); wave owns n-tile w
        f32x4 acc2[2] = { fz, fz };
        {
          const u16* w2p = pk + OFF_W2 + ((ei*4 + wid)*4)*512 + lane*8;
          #pragma unroll
          for (int kt = 0; kt < 4; ++kt) {
            bf16x8 b0 = ld_frag(w2p + kt*512);
            #pragma unroll
            for (int mt = 0; mt < 2; ++mt) {
              bf16x8 a = ld_frag(&h1frag[((mt*4 + kt)*64 + lane)*8]);
              acc2[mt] = mfma16(a, b0, acc2[mt]);
            }
          }
        }
        {
          int col = wid*16 + l15;
          float bias = eb2[ei*64 + col];
          int kt2 = col >> 5, h2 = (col >> 3) & 3, i2 = col & 7;
          #pragma unroll
          for (int mt = 0; mt < 2; ++mt)
            #pragma unroll
            for (int rr = 0; rr < 4; ++rr)
              h2frag[((mt*2 + kt2)*64 + rl + rr + 16*h2)*8 + i2] = f2bf(swishf(acc2[mt][rr] + bias));
        }
        __syncthreads();  // E2

        // GEMM3: h2(32x64) @ W3(64x64) -> e_pre into fbuf
        f32x4 acc3[2] = { fz, fz };
        {
          const u16* w3p = pk + OFF_W3 + ((ei*4 + wid)*2)*512 + lane*8;
          #pragma unroll
          for (int kt = 0; kt < 2; ++kt) {
            bf16x8 b0 = ld_frag(w3p + kt*512);
            #pragma unroll
            for (int mt = 0; mt < 2; ++mt) {
              bf16x8 a = ld_frag(&h2frag[((mt*2 + kt)*64 + lane)*8]);
              acc3[mt] = mfma16(a, b0, acc3[mt]);
            }
          }
        }
        {
          int col = wid*16 + l15;
          float bias = eb3[ei*64 + col];
          #pragma unroll
          for (int mt = 0; mt < 2; ++mt)
            #pragma unroll
            for (int rr = 0; rr < 4; ++rr)
              fbuf[(mt*16 + rl + rr)*72 + col] = acc3[mt][rr] + bias;
        }
        __syncthreads();  // E3

        // LayerNorm + self-gate diag + weighted aggregate (thread (r,q): 8 cols of row r)
        {
          float v[8];
          float4 fa = *(const float4*)&fbuf[r*72 + q*8];
          float4 fb = *(const float4*)&fbuf[r*72 + q*8 + 4];
          v[0]=fa.x; v[1]=fa.y; v[2]=fa.z; v[3]=fa.w;
          v[4]=fb.x; v[5]=fb.y; v[6]=fb.z; v[7]=fb.w;
          float s1 = 0.f;
          #pragma unroll
          for (int c = 0; c < 8; ++c) s1 += v[c];
          s1 += __shfl_xor(s1, 1); s1 += __shfl_xor(s1, 2); s1 += __shfl_xor(s1, 4);
          float mu = s1 * (1.f/64.f);
          float s2 = 0.f;
          #pragma unroll
          for (int c = 0; c < 8; ++c) { float d = v[c] - mu; s2 += d*d; }
          s2 += __shfl_xor(s2, 1); s2 += __shfl_xor(s2, 2); s2 += __shfl_xor(s2, 4);
          float rs = rsqrtf(s2 * (1.f/64.f) + 1e-5f);
          const float* lsp = lns + ei*64 + q*8;
          const float* lbp = lnb + ei*64 + q*8;
          const float* sgp = sgW + (t*64 + q*8)*4 + el;
          float swp = 0.f;
          #pragma unroll
          for (int c = 0; c < 8; ++c) {
            float eh = (v[c] - mu) * rs * lsp[c] + lbp[c];
            v[c] = eh;
            swp += eh * sgp[c*4];
          }
          swp += __shfl_xor(swp, 1); swp += __shfl_xor(swp, 2); swp += __shfl_xor(swp, 4);
          swp += sgb[t*4 + el];
          float fac = swp * gwbuf[r*4 + el];
          #pragma unroll
          for (int c = 0; c < 8; ++c) agg[c] += v[c] * fac;
        }
      }  // expert loop

      // ---------- tower via MFMA: agg(32x64) @ W1(64x64) -> swish -> @ W2(64x32) -> swish -> @ w3 ----------
      {
        uint4 wv;
        wv.x = f2bf2(agg[0], agg[1]);
        wv.y = f2bf2(agg[2], agg[3]);
        wv.z = f2bf2(agg[4], agg[5]);
        wv.w = f2bf2(agg[6], agg[7]);
        *(uint4*)&aggfrag[((mt_r*2 + (q>>2))*64 + r15 + 16*(q&3)) * 8] = wv;
      }
      __syncthreads();  // F

      {
        // T1: wave w owns n-tile w of 64
        f32x4 at1[2] = { fz, fz };
        const u16* tw1p = pk + OFF_TW1 + ((t*4 + wid)*2)*512 + lane*8;
        #pragma unroll
        for (int kt = 0; kt < 2; ++kt) {
          bf16x8 b0 = ld_frag(tw1p + kt*512);
          #pragma unroll
          for (int mt = 0; mt < 2; ++mt) {
            bf16x8 a = ld_frag(&aggfrag[((mt*2 + kt)*64 + lane)*8]);
            at1[mt] = mfma16(a, b0, at1[mt]);
          }
        }
        int colT = wid*16 + l15;
        float bias = twb1[t*64 + colT];
        int ktT = colT >> 5, hT = (colT >> 3) & 3, iT = colT & 7;
        #pragma unroll
        for (int mt = 0; mt < 2; ++mt)
          #pragma unroll
          for (int rr = 0; rr < 4; ++rr)
            th1frag[((mt*2 + ktT)*64 + rl + rr + 16*hT)*8 + iT] = f2bf(swishf(at1[mt][rr] + bias));
      }
      __syncthreads();  // G

      if (wid < 2) {
        // T2: waves 0,1 own the two 16-col tiles of 32
        f32x4 at2[2] = { fz, fz };
        const u16* tw2p = pk + OFF_TW2 + ((t*2 + wid)*2)*512 + lane*8;
        #pragma unroll
        for (int kt = 0; kt < 2; ++kt) {
          bf16x8 b0 = ld_frag(tw2p + kt*512);
          #pragma unroll
          for (int mt = 0; mt < 2; ++mt) {
            bf16x8 a = ld_frag(&th1frag[((mt*2 + kt)*64 + lane)*8]);
            at2[mt] = mfma16(a, b0, at2[mt]);
          }
        }
        int colU = wid*16 + l15;
        float b2  = twb2[t*32 + colU];
        float w3v = twW3[t*32 + colU];
        float px[8];
        #pragma unroll
        for (int mt = 0; mt < 2; ++mt)
          #pragma unroll
          for (int rr = 0; rr < 4; ++rr)
            px[mt*4 + rr] = swishf(at2[mt][rr] + b2) * w3v;
        #pragma unroll
        for (int k = 0; k < 8; ++k) {
          px[k] += __shfl_xor(px[k], 1);
          px[k] += __shfl_xor(px[k], 2);
          px[k] += __shfl_xor(px[k], 4);
          px[k] += __shfl_xor(px[k], 8);
        }
        if (l15 == 0) {
          #pragma unroll
          for (int mt = 0; mt < 2; ++mt)
            #pragma unroll
            for (int rr = 0; rr < 4; ++rr)
              arrp[wid*32 + mt*16 + rl + rr] = px[mt*4 + rr];
        }
      }
      __syncthreads();  // H

      if (tid < 32) {
        float x = arrp[tid] + arrp[32 + tid] + twb3[t];
        out[(size_t)(rowBase + tid)*4 + t] = 1.f / (1.f + __expf(-x));
      }
      // NO trailing barrier: next sub's first LDS writes (cmfrag staging, then accT/gateT
      // after barriers A/A2) are all ordered behind H relative to this sub's last readers.
    }
  }
}

extern "C" void kernel_launch(void* const* d_in, const int* in_sizes, int n_in,
                              void* d_out, int out_size, void* d_ws, size_t ws_size,
                              hipStream_t stream)
{
  (void)in_sizes; (void)n_in; (void)out_size; (void)ws_size;
  const float* zs   = (const float*)d_in[0];
  const float* zg0  = (const float*)d_in[1];
  const float* zg1  = (const float*)d_in[2];
  // d_in[3] = v : unused by the reference
  const float* eW1  = (const float*)d_in[4];
  const float* eb1  = (const float*)d_in[5];
  const float* eW2  = (const float*)d_in[6];
  const float* eb2  = (const float*)d_in[7];
  const float* eW3  = (const float*)d_in[8];
  const float* eb3  = (const float*)d_in[9];
  const float* lns  = (const float*)d_in[10];
  const float* lnb  = (const float*)d_in[11];
  const float* fgA  = (const float*)d_in[12];
  const float* fgB  = (const float*)d_in[13];
  const float* tgW1 = (const float*)d_in[14];
  const float* tgb1 = (const float*)d_in[15];
  const float* tgW2 = (const float*)d_in[16];
  const float* tgb2 = (const float*)d_in[17];
  const float* sgW  = (const float*)d_in[18];
  const float* sgb  = (const float*)d_in[19];
  const float* twW1 = (const float*)d_in[20];
  const float* twb1 = (const float*)d_in[21];
  const float* twW2 = (const float*)d_in[22];
  const float* twb2 = (const float*)d_in[23];
  const float* twW3 = (const float*)d_in[24];
  const float* twb3 = (const float*)d_in[25];

  u16* pkw = (u16*)d_ws;          // needs 819200 B
  float* outp = (float*)d_out;

  prep_pack<<<(NPACK + 255)/256, 256, 0, stream>>>(eW1, eW2, eW3, tgW1, twW1, twW2, fgA, fgB, pkw);
  home_main<<<65536/32, 256, 0, stream>>>(zs, zg0, zg1, tgW2, tgb1, tgb2,
      eb1, eb2, eb3, lns, lnb, sgW, sgb, twb1, twb2, twW3, twb3,
      pkw, outp);
}

// Round 9
// 413.197 us; speedup vs baseline: 1.8762x; 1.0130x over previous
//
#include <hip/hip_runtime.h>

typedef unsigned short u16;
typedef unsigned int   u32;
typedef __bf16 bf16x8 __attribute__((ext_vector_type(8)));
typedef float  f32x4  __attribute__((ext_vector_type(4)));

// packed-weight regions (bf16 elements) in d_ws
#define OFF_W2  196608
#define OFF_W3  245760
#define OFF_TG  270336
#define OFF_TW1 335872
#define OFF_TW2 352256
#define OFF_FGA 360448
#define OFF_FGB 376832
#define NPACK   409600

// native f32->bf16 (RNE): v_cvt_pk_bf16_f32
__device__ __forceinline__ u16 f2bf(float f) {
  union { __bf16 b; u16 u; } cv;
  cv.b = (__bf16)f;
  return cv.u;
}
__device__ __forceinline__ u32 f2bf2(float lo, float hi) {
  return (u32)f2bf(lo) | ((u32)f2bf(hi) << 16);
}
__device__ __forceinline__ float bf2f(u16 s) { return __uint_as_float(((u32)s) << 16); }
__device__ __forceinline__ float bflo(u32 p) { return __uint_as_float(p << 16); }
__device__ __forceinline__ float bfhi(u32 p) { return __uint_as_float(p & 0xffff0000u); }

union U4 { uint4 u; bf16x8 v; };
__device__ __forceinline__ bf16x8 ld_frag(const u16* p) {
  U4 t; t.u = *(const uint4*)p; return t.v;
}
__device__ __forceinline__ f32x4 mfma16(bf16x8 a, bf16x8 b, f32x4 c) {
  return __builtin_amdgcn_mfma_f32_16x16x32_bf16(a, b, c, 0, 0, 0);
}
__device__ __forceinline__ float swishf(float x) { return x / (1.f + __expf(-x)); }

// ---------------- weight repack: f32 row-major -> bf16 fragment order ----------------
// frag element (lane,i) of tile (nt,kt) = W[k][n], k = kt*32 + (lane>>4)*8 + i, n = nt*16 + (lane&15)
__global__ __launch_bounds__(256) void prep_pack(
    const float* __restrict__ eW1, const float* __restrict__ eW2,
    const float* __restrict__ eW3, const float* __restrict__ tgW1,
    const float* __restrict__ twW1, const float* __restrict__ twW2,
    const float* __restrict__ fgA, const float* __restrict__ fgB,
    u16* __restrict__ pk)
{
  int idx = blockIdx.x * 256 + threadIdx.x;
  if (idx >= NPACK) return;
  float v;
  if (idx < OFF_W2) {                 // exp_W1: [6][nt:8][kt:8][64][8]
    int i = idx & 7, lane = (idx >> 3) & 63, kt = (idx >> 9) & 7, nt = (idx >> 12) & 7, e = idx >> 15;
    int k = kt*32 + (lane>>4)*8 + i, n = nt*16 + (lane & 15);
    v = eW1[(e*256 + k)*128 + n];
  } else if (idx < OFF_W3) {          // exp_W2: [6][nt:4][kt:4][64][8]
    int j = idx - OFF_W2;
    int i = j & 7, lane = (j >> 3) & 63, kt = (j >> 9) & 3, nt = (j >> 11) & 3, e = j >> 13;
    int k = kt*32 + (lane>>4)*8 + i, n = nt*16 + (lane & 15);
    v = eW2[(e*128 + k)*64 + n];
  } else if (idx < OFF_TG) {          // exp_W3: [6][nt:4][kt:2][64][8]
    int j = idx - OFF_W3;
    int i = j & 7, lane = (j >> 3) & 63, kt = (j >> 9) & 1, nt = (j >> 10) & 3, e = j >> 12;
    int k = kt*32 + (lane>>4)*8 + i, n = nt*16 + (lane & 15);
    v = eW3[(e*64 + k)*64 + n];
  } else if (idx < OFF_TW1) {         // tg_W1: [4][nt:4][kt:8][64][8]
    int j = idx - OFF_TG;
    int i = j & 7, lane = (j >> 3) & 63, kt = (j >> 9) & 7, nt = (j >> 12) & 3, t = j >> 14;
    int k = kt*32 + (lane>>4)*8 + i, n = nt*16 + (lane & 15);
    v = tgW1[(t*256 + k)*64 + n];
  } else if (idx < OFF_TW2) {         // tw_W1: [4][nt:4][kt:2][64][8]
    int j = idx - OFF_TW1;
    int i = j & 7, lane = (j >> 3) & 63, kt = (j >> 9) & 1, nt = (j >> 10) & 3, t = j >> 12;
    int k = kt*32 + (lane>>4)*8 + i, n = nt*16 + (lane & 15);
    v = twW1[(t*64 + k)*64 + n];
  } else if (idx < OFF_FGA) {         // tw_W2: [4][nt:2][kt:2][64][8]
    int j = idx - OFF_TW2;
    int i = j & 7, lane = (j >> 3) & 63, kt = (j >> 9) & 1, nt = (j >> 10) & 1, t = j >> 11;
    int k = kt*32 + (lane>>4)*8 + i, n = nt*16 + (lane & 15);
    v = twW2[(t*64 + k)*32 + n];
  } else if (idx < OFF_FGB) {         // fgA^T A-frags: [4][kt:8][64][8]; A[m][k]=fgA[k][m], m<8 else 0
    int j = idx - OFF_FGA;
    int i = j & 7, lane = (j >> 3) & 63, kt = (j >> 9) & 7, t = j >> 12;
    int m = lane & 15, k = kt*32 + (lane>>4)*8 + i;
    v = (m < 8) ? fgA[(t*256 + k)*8 + m] : 0.f;
  } else {                            // fgB^T A-frags: [4][mtile:16][64][8]; A[m][kr]=fgB[kr][m], kr<8 else 0
    int j = idx - OFF_FGB;
    int i = j & 7, lane = (j >> 3) & 63, mtl = (j >> 9) & 15, t = j >> 13;
    int m = mtl*16 + (lane & 15), kr = (lane>>4)*8 + i;
    v = (kr < 8) ? fgB[t*2048 + kr*256 + m] : 0.f;
  }
  pk[idx] = f2bf(v);
}

// ---------------- fused main kernel: 32 rows/block, loops 4 tasks ----------------
// r6/r8-proven shape: 256 threads, launch_bounds(256,3) -> 84 VGPR budget (r8 actual: 72), no spill.
// r9 changes vs r8 (both target the stall fraction; nothing else touched):
//  (1) fbuf pitch 72 -> 68 f32: 68%32=4 -> LN b128 reads spread all 8 four-bank groups at
//      2 lanes/bank (free, m136); tg1/GEMM3 scalar epilogue writes cover 32 banks 2/bank (free).
//      (72%32=8 made LN reads ~8-way and epilogue writes 4-way conflicted.)
//  (2) LDS 40960 -> 40192 B: r8's exact-fit 4x40960=160KiB evidently failed (occupancy 31.7%
//      = 3 blocks/CU); 3.6 KB slack should let 4 blocks reside.
__global__ __launch_bounds__(256, 3) void home_main(
    const float* __restrict__ zs, const float* __restrict__ zg0, const float* __restrict__ zg1,
    const float* __restrict__ tgW2, const float* __restrict__ tgb1, const float* __restrict__ tgb2,
    const float* __restrict__ eb1, const float* __restrict__ eb2, const float* __restrict__ eb3,
    const float* __restrict__ lns, const float* __restrict__ lnb,
    const float* __restrict__ sgW, const float* __restrict__ sgb,
    const float* __restrict__ twb1, const float* __restrict__ twb2,
    const float* __restrict__ twW3, const float* __restrict__ twb3,
    const u16* __restrict__ pk, float* __restrict__ out)
{
  __shared__ __align__(16) u16   cmfrag[2*8*64*8];   // 16384 B  cm A-frags [mt2][kt8][64][8]; pre-z then gated
  __shared__ __align__(16) char  region2[22016];     // gemm: h1frag|h2frag|fbuf  ||  gate: accT|gateT
  __shared__ __align__(16) float gwbuf[128];         //  gate weights ; alias tower partials
  __shared__ __align__(16) float smallw[320];        //  tg_W2^T swizzled

  u16*   h1frag = (u16*)region2;                // 9216 B (4608 u16) [mt2][kt4][64][8]
  u16*   h2frag = (u16*)(region2 + 9216);       // 4096 B [mt2][kt2][64][8]
  float* fbuf   = (float*)(region2 + 13312);    // 8704 B [32][68]
  float* accT   = (float*)region2;              // [8][34] f32 = 1088 B   (gate phase)
  u16*   gateT  = (u16*)(region2 + 1280);       // [32][264] bf16 = 16896 B (gate phase)
  u16*   aggfrag = h2frag;                      // [mt2][kt2][64][8]
  u16*   th1frag = (u16*)fbuf;                  // [mt2][kt2][64][8]
  float* arrp    = gwbuf;                       // [2][32] tower partials

  const int tid  = threadIdx.x;
  const int lane = tid & 63;
  const int wid  = tid >> 6;       // wave 0..3
  const int r    = tid >> 3;       // row 0..31
  const int q    = tid & 7;        // eighth of the 256-d feature
  const int rowBase = blockIdx.x * 32;
  const int mt_r = r >> 4, r15 = r & 15;
  const int rl   = (lane >> 4) * 4;   // C-layout row offset
  const int l15  = lane & 15;
  const f32x4 fz = {0.f, 0.f, 0.f, 0.f};

  #pragma unroll 1
  for (int pair = 0; pair < 2; ++pair) {
    const int g = pair;
    #pragma unroll 1
    for (int sub = 0; sub < 2; ++sub) {
      const int t = pair * 2 + sub;

      // ---------- stage cm_pre (bf16) directly into cmfrag + tgW2 into LDS ----------
      {
        const float* zsrc = (q < 4)
          ? (zs + (size_t)(rowBase + r) * 128 + q * 32)
          : ((pair ? zg1 : zg0) + (size_t)(rowBase + r) * 128 + (q - 4) * 32);
        #pragma unroll
        for (int h = 0; h < 4; ++h) {
          float4 a = ((const float4*)zsrc)[2*h], b4 = ((const float4*)zsrc)[2*h+1];
          uint4 wv;
          wv.x = f2bf2(a.x, a.y);
          wv.y = f2bf2(a.z, a.w);
          wv.z = f2bf2(b4.x, b4.y);
          wv.w = f2bf2(b4.z, b4.w);
          *(uint4*)&cmfrag[((mt_r*8 + q)*64 + r15 + 16*h)*8] = wv;
        }
      }
      {
        int e = tid >> 6, c = tid & 63, half = c >> 5, cl = c & 31;
        smallw[(e*2 + half)*36 + cl] = tgW2[t*256 + c*4 + e];
      }
      __syncthreads();   // A

      // ---------- gate step 1 (waves 0,1): accT(8x32) = fgA^T @ cm_pre^T ----------
      if (wid < 2) {
        f32x4 d1 = fz;
        const u16* ap = pk + OFF_FGA + (t*8)*512 + lane*8;
        #pragma unroll
        for (int kt = 0; kt < 8; ++kt) {
          bf16x8 af = ld_frag(ap + kt*512);
          bf16x8 bf = ld_frag(&cmfrag[((wid*8 + kt)*64 + lane)*8]);
          d1 = mfma16(af, bf, d1);
        }
        if (rl < 8) {      // ranks 0-7 live in lane groups 0,1
          #pragma unroll
          for (int rr = 0; rr < 4; ++rr)
            accT[(rl + rr)*34 + wid*16 + l15] = d1[rr];
        }
      }
      __syncthreads();   // A2

      // ---------- gate step 2 (all waves): logitsT = fgB^T @ accT ; gate = 2*sigmoid -> gateT ----------
      {
        // build B-frags (K=32, only k<8 nonzero -> lane group 0 holds data)
        U4 b0u, b1u;
        if (lane < 16) {
          float v0[8], v1[8];
          #pragma unroll
          for (int i = 0; i < 8; ++i) {
            v0[i] = accT[i*34 + l15];
            v1[i] = accT[i*34 + 16 + l15];
          }
          b0u.u.x = f2bf2(v0[0], v0[1]); b0u.u.y = f2bf2(v0[2], v0[3]);
          b0u.u.z = f2bf2(v0[4], v0[5]); b0u.u.w = f2bf2(v0[6], v0[7]);
          b1u.u.x = f2bf2(v1[0], v1[1]); b1u.u.y = f2bf2(v1[2], v1[3]);
          b1u.u.z = f2bf2(v1[4], v1[5]); b1u.u.w = f2bf2(v1[6], v1[7]);
        } else {
          b0u.u = make_uint4(0, 0, 0, 0);
          b1u.u = make_uint4(0, 0, 0, 0);
        }
        #pragma unroll
        for (int mt4 = 0; mt4 < 4; ++mt4) {
          int mtile = wid*4 + mt4;
          bf16x8 af = ld_frag(pk + OFF_FGB + (t*16 + mtile)*512 + lane*8);
          f32x4 d0 = mfma16(af, b0u.v, fz);
          f32x4 d1 = mfma16(af, b1u.v, fz);
          int fbase = mtile*16 + rl;
          {
            float g0 = 2.f / (1.f + __expf(-d0[0]));
            float g1 = 2.f / (1.f + __expf(-d0[1]));
            float g2 = 2.f / (1.f + __expf(-d0[2]));
            float g3 = 2.f / (1.f + __expf(-d0[3]));
            int rowc = l15;
            *(u32*)&gateT[rowc*264 + fbase]     = f2bf2(g0, g1);
            *(u32*)&gateT[rowc*264 + fbase + 2] = f2bf2(g2, g3);
          }
          {
            float g0 = 2.f / (1.f + __expf(-d1[0]));
            float g1 = 2.f / (1.f + __expf(-d1[1]));
            float g2 = 2.f / (1.f + __expf(-d1[2]));
            float g3 = 2.f / (1.f + __expf(-d1[3]));
            int rowc = 16 + l15;
            *(u32*)&gateT[rowc*264 + fbase]     = f2bf2(g0, g1);
            *(u32*)&gateT[rowc*264 + fbase + 2] = f2bf2(g2, g3);
          }
        }
      }
      __syncthreads();   // A3

      // ---------- gate apply (in-place on cmfrag); thread (r,q) owns row r, features q*32.. ----------
      {
        const int gbase = r*264 + q*32;
        #pragma unroll
        for (int h = 0; h < 4; ++h) {
          u16* cp = &cmfrag[((mt_r*8 + q)*64 + r15 + 16*h)*8];
          uint4 zv = *(const uint4*)cp;
          uint4 gv = *(const uint4*)&gateT[gbase + h*8];
          uint4 wv;
          wv.x = f2bf2(bflo(zv.x)*bflo(gv.x), bfhi(zv.x)*bfhi(gv.x));
          wv.y = f2bf2(bflo(zv.y)*bflo(gv.y), bfhi(zv.y)*bfhi(gv.y));
          wv.z = f2bf2(bflo(zv.z)*bflo(gv.z), bfhi(zv.z)*bfhi(gv.z));
          wv.w = f2bf2(bflo(zv.w)*bflo(gv.w), bfhi(zv.w)*bfhi(gv.w));
          *(uint4*)cp = wv;
        }
      }
      __syncthreads();   // B

      // ---------- task gate layer1: gh = swish(cm @ tg_W1 + b); wave w owns n-tile w ----------
      {
        f32x4 accg[2] = { fz, fz };
        const u16* wp = pk + OFF_TG + ((t*4 + wid)*8)*512 + lane*8;
        #pragma unroll
        for (int kt = 0; kt < 8; ++kt) {
          bf16x8 bfr = ld_frag(wp + kt*512);
          #pragma unroll
          for (int mt = 0; mt < 2; ++mt) {
            bf16x8 afr = ld_frag(&cmfrag[((mt*8 + kt)*64 + lane)*8]);
            accg[mt] = mfma16(afr, bfr, accg[mt]);
          }
        }
        int colg = wid*16 + l15;
        float bias = tgb1[t*64 + colg];
        #pragma unroll
        for (int mt = 0; mt < 2; ++mt)
          #pragma unroll
          for (int rr = 0; rr < 4; ++rr)
            fbuf[(mt*16 + rl + rr)*68 + colg] = swishf(accg[mt][rr] + bias);
      }
      __syncthreads();   // C

      // ---------- task gate layer2 + softmax (lanes q,q+4 split the 64-dim dot) ----------
      {
        int e = q & 3, half = q >> 2;
        float part = 0.f;
        #pragma unroll
        for (int cj = 0; cj < 8; ++cj) {
          float4 g4 = *(const float4*)&fbuf[r*68 + half*32 + cj*4];
          float4 w4 = *(const float4*)&smallw[(e*2 + half)*36 + cj*4];
          part += g4.x*w4.x + g4.y*w4.y + g4.z*w4.z + g4.w*w4.w;
        }
        part += __shfl_xor(part, 4);
        float logit = part + tgb2[t*4 + e];
        float mx = fmaxf(logit, __shfl_xor(logit, 1));
        mx = fmaxf(mx, __shfl_xor(mx, 2));
        float ex = __expf(logit - mx);
        float sm = ex + __shfl_xor(ex, 1);
        sm += __shfl_xor(sm, 2);
        if (q < 4) gwbuf[r*4 + q] = ex / sm;
      }
      // NO barrier: gwbuf's first reader (LN, el=0) is 3 barriers (E1,E2,E3) downstream;
      // GEMM1 writes h1frag (gateT/accT dead since barrier B).

      // ---------- expert loop ----------
      float agg[8];
      #pragma unroll
      for (int c = 0; c < 8; ++c) agg[c] = 0.f;

      #pragma unroll 1
      for (int el = 0; el < 4; ++el) {
        const int ei = (el < 2) ? el : (el + 2*g);

        // GEMM1: cm(32x256) @ W1(256x128); wave owns n-tiles 2w,2w+1
        f32x4 acc1[2][2];
        #pragma unroll
        for (int mt = 0; mt < 2; ++mt) { acc1[mt][0] = fz; acc1[mt][1] = fz; }
        {
          const u16* w1p = pk + ((ei*8 + 2*wid)*8)*512 + lane*8;
          #pragma unroll
          for (int kt = 0; kt < 8; ++kt) {
            bf16x8 b0 = ld_frag(w1p + kt*512);
            bf16x8 b1 = ld_frag(w1p + 4096 + kt*512);
            #pragma unroll
            for (int mt = 0; mt < 2; ++mt) {
              bf16x8 a = ld_frag(&cmfrag[((mt*8 + kt)*64 + lane)*8]);
              acc1[mt][0] = mfma16(a, b0, acc1[mt][0]);
              acc1[mt][1] = mfma16(a, b1, acc1[mt][1]);
            }
          }
        }
        #pragma unroll
        for (int nn = 0; nn < 2; ++nn) {
          int col = (2*wid + nn)*16 + l15;
          float bias = eb1[ei*128 + col];
          int kt2 = col >> 5, h2 = (col >> 3) & 3, i2 = col & 7;
          #pragma unroll
          for (int mt = 0; mt < 2; ++mt)
            #pragma unroll
            for (int rr = 0; rr < 4; ++rr)
              h1frag[((mt*4 + kt2)*64 + rl + rr + 16*h2)*8 + i2] = f2bf(swishf(acc1[mt][nn][rr] + bias));
        }
        __syncthreads();  // E1

        // GEMM2: h1(32x128) @ W2(128x64); wave owns n-tile w
        f32x4 acc2[2] = { fz, fz };
        {
          const u16* w2p = pk + OFF_W2 + ((ei*4 + wid)*4)*512 + lane*8;
          #pragma unroll
          for (int kt = 0; kt < 4; ++kt) {
            bf16x8 b0 = ld_frag(w2p + kt*512);
            #pragma unroll
            for (int mt = 0; mt < 2; ++mt) {
              bf16x8 a = ld_frag(&h1frag[((mt*4 + kt)*64 + lane)*8]);
              acc2[mt] = mfma16(a, b0, acc2[mt]);
            }
          }
        }
        {
          int col = wid*16 + l15;
          float bias = eb2[ei*64 + col];
          int kt2 = col >> 5, h2 = (col >> 3) & 3, i2 = col & 7;
          #pragma unroll
          for (int mt = 0; mt < 2; ++mt)
            #pragma unroll
            for (int rr = 0; rr < 4; ++rr)
              h2frag[((mt*2 + kt2)*64 + rl + rr + 16*h2)*8 + i2] = f2bf(swishf(acc2[mt][rr] + bias));
        }
        __syncthreads();  // E2

        // GEMM3: h2(32x64) @ W3(64x64) -> e_pre into fbuf
        f32x4 acc3[2] = { fz, fz };
        {
          const u16* w3p = pk + OFF_W3 + ((ei*4 + wid)*2)*512 + lane*8;
          #pragma unroll
          for (int kt = 0; kt < 2; ++kt) {
            bf16x8 b0 = ld_frag(w3p + kt*512);
            #pragma unroll
            for (int mt = 0; mt < 2; ++mt) {
              bf16x8 a = ld_frag(&h2frag[((mt*2 + kt)*64 + lane)*8]);
              acc3[mt] = mfma16(a, b0, acc3[mt]);
            }
          }
        }
        {
          int col = wid*16 + l15;
          float bias = eb3[ei*64 + col];
          #pragma unroll
          for (int mt = 0; mt < 2; ++mt)
            #pragma unroll
            for (int rr = 0; rr < 4; ++rr)
              fbuf[(mt*16 + rl + rr)*68 + col] = acc3[mt][rr] + bias;
        }
        __syncthreads();  // E3

        // LayerNorm + self-gate diag + weighted aggregate (thread (r,q): 8 cols of row r)
        {
          float v[8];
          float4 fa = *(const float4*)&fbuf[r*68 + q*8];
          float4 fb = *(const float4*)&fbuf[r*68 + q*8 + 4];
          v[0]=fa.x; v[1]=fa.y; v[2]=fa.z; v[3]=fa.w;
          v[4]=fb.x; v[5]=fb.y; v[6]=fb.z; v[7]=fb.w;
          float s1 = 0.f;
          #pragma unroll
          for (int c = 0; c < 8; ++c) s1 += v[c];
          s1 += __shfl_xor(s1, 1); s1 += __shfl_xor(s1, 2); s1 += __shfl_xor(s1, 4);
          float mu = s1 * (1.f/64.f);
          float s2 = 0.f;
          #pragma unroll
          for (int c = 0; c < 8; ++c) { float d = v[c] - mu; s2 += d*d; }
          s2 += __shfl_xor(s2, 1); s2 += __shfl_xor(s2, 2); s2 += __shfl_xor(s2, 4);
          float rs = rsqrtf(s2 * (1.f/64.f) + 1e-5f);
          const float* lsp = lns + ei*64 + q*8;
          const float* lbp = lnb + ei*64 + q*8;
          const float* sgp = sgW + (t*64 + q*8)*4 + el;
          float swp = 0.f;
          #pragma unroll
          for (int c = 0; c < 8; ++c) {
            float eh = (v[c] - mu) * rs * lsp[c] + lbp[c];
            v[c] = eh;
            swp += eh * sgp[c*4];
          }
          swp += __shfl_xor(swp, 1); swp += __shfl_xor(swp, 2); swp += __shfl_xor(swp, 4);
          swp += sgb[t*4 + el];
          float fac = swp * gwbuf[r*4 + el];
          #pragma unroll
          for (int c = 0; c < 8; ++c) agg[c] += v[c] * fac;
        }
      }  // expert loop

      // ---------- tower via MFMA: agg(32x64) @ W1(64x64) -> swish -> @ W2(64x32) -> swish -> @ w3 ----------
      {
        uint4 wv;
        wv.x = f2bf2(agg[0], agg[1]);
        wv.y = f2bf2(agg[2], agg[3]);
        wv.z = f2bf2(agg[4], agg[5]);
        wv.w = f2bf2(agg[6], agg[7]);
        *(uint4*)&aggfrag[((mt_r*2 + (q>>2))*64 + r15 + 16*(q&3)) * 8] = wv;
      }
      __syncthreads();  // F

      {
        // T1: wave w owns n-tile w of 64
        f32x4 at1[2] = { fz, fz };
        const u16* tw1p = pk + OFF_TW1 + ((t*4 + wid)*2)*512 + lane*8;
        #pragma unroll
        for (int kt = 0; kt < 2; ++kt) {
          bf16x8 b0 = ld_frag(tw1p + kt*512);
          #pragma unroll
          for (int mt = 0; mt < 2; ++mt) {
            bf16x8 a = ld_frag(&aggfrag[((mt*2 + kt)*64 + lane)*8]);
            at1[mt] = mfma16(a, b0, at1[mt]);
          }
        }
        int colT = wid*16 + l15;
        float bias = twb1[t*64 + colT];
        int ktT = colT >> 5, hT = (colT >> 3) & 3, iT = colT & 7;
        #pragma unroll
        for (int mt = 0; mt < 2; ++mt)
          #pragma unroll
          for (int rr = 0; rr < 4; ++rr)
            th1frag[((mt*2 + ktT)*64 + rl + rr + 16*hT)*8 + iT] = f2bf(swishf(at1[mt][rr] + bias));
      }
      __syncthreads();  // G

      if (wid < 2) {
        // T2: waves 0,1 own the two 16-col tiles of 32
        f32x4 at2[2] = { fz, fz };
        const u16* tw2p = pk + OFF_TW2 + ((t*2 + wid)*2)*512 + lane*8;
        #pragma unroll
        for (int kt = 0; kt < 2; ++kt) {
          bf16x8 b0 = ld_frag(tw2p + kt*512);
          #pragma unroll
          for (int mt = 0; mt < 2; ++mt) {
            bf16x8 a = ld_frag(&th1frag[((mt*2 + kt)*64 + lane)*8]);
            at2[mt] = mfma16(a, b0, at2[mt]);
          }
        }
        int colU = wid*16 + l15;
        float b2  = twb2[t*32 + colU];
        float w3v = twW3[t*32 + colU];
        float px[8];
        #pragma unroll
        for (int mt = 0; mt < 2; ++mt)
          #pragma unroll
          for (int rr = 0; rr < 4; ++rr)
            px[mt*4 + rr] = swishf(at2[mt][rr] + b2) * w3v;
        #pragma unroll
        for (int k = 0; k < 8; ++k) {
          px[k] += __shfl_xor(px[k], 1);
          px[k] += __shfl_xor(px[k], 2);
          px[k] += __shfl_xor(px[k], 4);
          px[k] += __shfl_xor(px[k], 8);
        }
        if (l15 == 0) {
          #pragma unroll
          for (int mt = 0; mt < 2; ++mt)
            #pragma unroll
            for (int rr = 0; rr < 4; ++rr)
              arrp[wid*32 + mt*16 + rl + rr] = px[mt*4 + rr];
        }
      }
      __syncthreads();  // H

      if (tid < 32) {
        float x = arrp[tid] + arrp[32 + tid] + twb3[t];
        out[(size_t)(rowBase + tid)*4 + t] = 1.f / (1.f + __expf(-x));
      }
      // NO trailing barrier: next sub's first LDS writes (cmfrag staging, then accT/gateT
      // after barriers A/A2) are all ordered behind H relative to this sub's last readers.
    }
  }
}

extern "C" void kernel_launch(void* const* d_in, const int* in_sizes, int n_in,
                              void* d_out, int out_size, void* d_ws, size_t ws_size,
                              hipStream_t stream)
{
  (void)in_sizes; (void)n_in; (void)out_size; (void)ws_size;
  const float* zs   = (const float*)d_in[0];
  const float* zg0  = (const float*)d_in[1];
  const float* zg1  = (const float*)d_in[2];
  // d_in[3] = v : unused by the reference
  const float* eW1  = (const float*)d_in[4];
  const float* eb1  = (const float*)d_in[5];
  const float* eW2  = (const float*)d_in[6];
  const float* eb2  = (const float*)d_in[7];
  const float* eW3  = (const float*)d_in[8];
  const float* eb3  = (const float*)d_in[9];
  const float* lns  = (const float*)d_in[10];
  const float* lnb  = (const float*)d_in[11];
  const float* fgA  = (const float*)d_in[12];
  const float* fgB  = (const float*)d_in[13];
  const float* tgW1 = (const float*)d_in[14];
  const float* tgb1 = (const float*)d_in[15];
  const float* tgW2 = (const float*)d_in[16];
  const float* tgb2 = (const float*)d_in[17];
  const float* sgW  = (const float*)d_in[18];
  const float* sgb  = (const float*)d_in[19];
  const float* twW1 = (const float*)d_in[20];
  const float* twb1 = (const float*)d_in[21];
  const float* twW2 = (const float*)d_in[22];
  const float* twb2 = (const float*)d_in[23];
  const float* twW3 = (const float*)d_in[24];
  const float* twb3 = (const float*)d_in[25];

  u16* pkw = (u16*)d_ws;          // needs 819200 B
  float* outp = (float*)d_out;

  prep_pack<<<(NPACK + 255)/256, 256, 0, stream>>>(eW1, eW2, eW3, tgW1, twW1, twW2, fgA, fgB, pkw);
  home_main<<<65536/32, 256, 0, stream>>>(zs, zg0, zg1, tgW2, tgb1, tgb2,
      eb1, eb2, eb3, lns, lnb, sgW, sgb, twb1, twb2, twW3, twb3,
      pkw, outp);
}

// Round 10
// 395.149 us; speedup vs baseline: 1.9619x; 1.0457x over previous
//
#include <hip/hip_runtime.h>

typedef unsigned short u16;
typedef unsigned int   u32;
typedef __bf16 bf16x8 __attribute__((ext_vector_type(8)));
typedef float  f32x4  __attribute__((ext_vector_type(4)));

// packed-weight regions (bf16 elements) in d_ws
#define OFF_W2  196608
#define OFF_W3  245760
#define OFF_TG  270336
#define OFF_TW1 335872
#define OFF_TW2 352256
#define OFF_FGA 360448
#define OFF_FGB 376832
#define NPACK   409600

// native f32->bf16 (RNE): v_cvt_pk_bf16_f32
__device__ __forceinline__ u16 f2bf(float f) {
  union { __bf16 b; u16 u; } cv;
  cv.b = (__bf16)f;
  return cv.u;
}
__device__ __forceinline__ u32 f2bf2(float lo, float hi) {
  return (u32)f2bf(lo) | ((u32)f2bf(hi) << 16);
}
__device__ __forceinline__ float bf2f(u16 s) { return __uint_as_float(((u32)s) << 16); }
__device__ __forceinline__ float bflo(u32 p) { return __uint_as_float(p << 16); }
__device__ __forceinline__ float bfhi(u32 p) { return __uint_as_float(p & 0xffff0000u); }

union U4 { uint4 u; bf16x8 v; };
__device__ __forceinline__ bf16x8 ld_frag(const u16* p) {
  U4 t; t.u = *(const uint4*)p; return t.v;
}
__device__ __forceinline__ f32x4 mfma16(bf16x8 a, bf16x8 b, f32x4 c) {
  return __builtin_amdgcn_mfma_f32_16x16x32_bf16(a, b, c, 0, 0, 0);
}
__device__ __forceinline__ float swishf(float x) { return x / (1.f + __expf(-x)); }

// ---------------- weight repack: f32 row-major -> bf16 fragment order ----------------
// frag element (lane,i) of tile (nt,kt) = W[k][n], k = kt*32 + (lane>>4)*8 + i, n = nt*16 + (lane&15)
__global__ __launch_bounds__(256) void prep_pack(
    const float* __restrict__ eW1, const float* __restrict__ eW2,
    const float* __restrict__ eW3, const float* __restrict__ tgW1,
    const float* __restrict__ twW1, const float* __restrict__ twW2,
    const float* __restrict__ fgA, const float* __restrict__ fgB,
    u16* __restrict__ pk)
{
  int idx = blockIdx.x * 256 + threadIdx.x;
  if (idx >= NPACK) return;
  float v;
  if (idx < OFF_W2) {                 // exp_W1: [6][nt:8][kt:8][64][8]
    int i = idx & 7, lane = (idx >> 3) & 63, kt = (idx >> 9) & 7, nt = (idx >> 12) & 7, e = idx >> 15;
    int k = kt*32 + (lane>>4)*8 + i, n = nt*16 + (lane & 15);
    v = eW1[(e*256 + k)*128 + n];
  } else if (idx < OFF_W3) {          // exp_W2: [6][nt:4][kt:4][64][8]
    int j = idx - OFF_W2;
    int i = j & 7, lane = (j >> 3) & 63, kt = (j >> 9) & 3, nt = (j >> 11) & 3, e = j >> 13;
    int k = kt*32 + (lane>>4)*8 + i, n = nt*16 + (lane & 15);
    v = eW2[(e*128 + k)*64 + n];
  } else if (idx < OFF_TG) {          // exp_W3: [6][nt:4][kt:2][64][8]
    int j = idx - OFF_W3;
    int i = j & 7, lane = (j >> 3) & 63, kt = (j >> 9) & 1, nt = (j >> 10) & 3, e = j >> 12;
    int k = kt*32 + (lane>>4)*8 + i, n = nt*16 + (lane & 15);
    v = eW3[(e*64 + k)*64 + n];
  } else if (idx < OFF_TW1) {         // tg_W1: [4][nt:4][kt:8][64][8]
    int j = idx - OFF_TG;
    int i = j & 7, lane = (j >> 3) & 63, kt = (j >> 9) & 7, nt = (j >> 12) & 3, t = j >> 14;
    int k = kt*32 + (lane>>4)*8 + i, n = nt*16 + (lane & 15);
    v = tgW1[(t*256 + k)*64 + n];
  } else if (idx < OFF_TW2) {         // tw_W1: [4][nt:4][kt:2][64][8]
    int j = idx - OFF_TW1;
    int i = j & 7, lane = (j >> 3) & 63, kt = (j >> 9) & 1, nt = (j >> 10) & 3, t = j >> 12;
    int k = kt*32 + (lane>>4)*8 + i, n = nt*16 + (lane & 15);
    v = twW1[(t*64 + k)*64 + n];
  } else if (idx < OFF_FGA) {         // tw_W2: [4][nt:2][kt:2][64][8]
    int j = idx - OFF_TW2;
    int i = j & 7, lane = (j >> 3) & 63, kt = (j >> 9) & 1, nt = (j >> 10) & 1, t = j >> 11;
    int k = kt*32 + (lane>>4)*8 + i, n = nt*16 + (lane & 15);
    v = twW2[(t*64 + k)*32 + n];
  } else if (idx < OFF_FGB) {         // fgA^T A-frags: [4][kt:8][64][8]; A[m][k]=fgA[k][m], m<8 else 0
    int j = idx - OFF_FGA;
    int i = j & 7, lane = (j >> 3) & 63, kt = (j >> 9) & 7, t = j >> 12;
    int m = lane & 15, k = kt*32 + (lane>>4)*8 + i;
    v = (m < 8) ? fgA[(t*256 + k)*8 + m] : 0.f;
  } else {                            // fgB^T A-frags: [4][mtile:16][64][8]; A[m][kr]=fgB[kr][m], kr<8 else 0
    int j = idx - OFF_FGB;
    int i = j & 7, lane = (j >> 3) & 63, mtl = (j >> 9) & 15, t = j >> 13;
    int m = mtl*16 + (lane & 15), kr = (lane>>4)*8 + i;
    v = (kr < 8) ? fgB[t*2048 + kr*256 + m] : 0.f;
  }
  pk[idx] = f2bf(v);
}

// ---------------- fused main kernel: 32 rows/block, loops 4 tasks ----------------
// r6/r8/r9-proven shape: 256 threads, launch_bounds(256,3) -> 84 VGPR budget, no spill, LDS 40448.
// r10 changes (latency-structure, nothing else):
//  (1) Cross-barrier weight prefetch: B-frags are consumed from REGISTERS, so issue their
//      global loads BEFORE the preceding __syncthreads -> L2 latency (~200-600cy) hides under
//      the barrier wait instead of serializing each phase start. Depth <= 16 VGPR in flight.
//  (2) T2 on wave 0 alone (both col tiles) + direct out write: deletes barrier H + arrp
//      round-trip; waves 1-3 run ahead into next sub's staging (cmfrag/smallw only, ordered
//      by barrier A before any reader).
__global__ __launch_bounds__(256, 3) void home_main(
    const float* __restrict__ zs, const float* __restrict__ zg0, const float* __restrict__ zg1,
    const float* __restrict__ tgW2, const float* __restrict__ tgb1, const float* __restrict__ tgb2,
    const float* __restrict__ eb1, const float* __restrict__ eb2, const float* __restrict__ eb3,
    const float* __restrict__ lns, const float* __restrict__ lnb,
    const float* __restrict__ sgW, const float* __restrict__ sgb,
    const float* __restrict__ twb1, const float* __restrict__ twb2,
    const float* __restrict__ twW3, const float* __restrict__ twb3,
    const u16* __restrict__ pk, float* __restrict__ out)
{
  __shared__ __align__(16) u16   cmfrag[2*8*64*8];   // 16384 B  cm A-frags [mt2][kt8][64][8]; pre-z then gated
  __shared__ __align__(16) char  region2[22016];     // gemm: h1frag|h2frag|fbuf  ||  gate: accT|gateT
  __shared__ __align__(16) float gwbuf[128];         //  softmax gate weights [32][4]
  __shared__ __align__(16) float smallw[320];        //  tg_W2^T swizzled

  u16*   h1frag = (u16*)region2;                // 9216 B (4608 u16) [mt2][kt4][64][8]
  u16*   h2frag = (u16*)(region2 + 9216);       // 4096 B [mt2][kt2][64][8]
  float* fbuf   = (float*)(region2 + 13312);    // 8704 B [32][68]
  float* accT   = (float*)region2;              // [8][34] f32 = 1088 B   (gate phase)
  u16*   gateT  = (u16*)(region2 + 1280);       // [32][264] bf16 = 16896 B (gate phase)
  u16*   aggfrag = h2frag;                      // [mt2][kt2][64][8]
  u16*   th1frag = (u16*)fbuf;                  // [mt2][kt2][64][8]

  const int tid  = threadIdx.x;
  const int lane = tid & 63;
  const int wid  = tid >> 6;       // wave 0..3
  const int r    = tid >> 3;       // row 0..31
  const int q    = tid & 7;        // eighth of the 256-d feature
  const int rowBase = blockIdx.x * 32;
  const int mt_r = r >> 4, r15 = r & 15;
  const int rl   = (lane >> 4) * 4;   // C-layout row offset
  const int l15  = lane & 15;
  const f32x4 fz = {0.f, 0.f, 0.f, 0.f};

  #pragma unroll 1
  for (int pair = 0; pair < 2; ++pair) {
    const int g = pair;
    #pragma unroll 1
    for (int sub = 0; sub < 2; ++sub) {
      const int t = pair * 2 + sub;

      // ---------- stage cm_pre (bf16) directly into cmfrag + tgW2 into LDS ----------
      {
        const float* zsrc = (q < 4)
          ? (zs + (size_t)(rowBase + r) * 128 + q * 32)
          : ((pair ? zg1 : zg0) + (size_t)(rowBase + r) * 128 + (q - 4) * 32);
        #pragma unroll
        for (int h = 0; h < 4; ++h) {
          float4 a = ((const float4*)zsrc)[2*h], b4 = ((const float4*)zsrc)[2*h+1];
          uint4 wv;
          wv.x = f2bf2(a.x, a.y);
          wv.y = f2bf2(a.z, a.w);
          wv.z = f2bf2(b4.x, b4.y);
          wv.w = f2bf2(b4.z, b4.w);
          *(uint4*)&cmfrag[((mt_r*8 + q)*64 + r15 + 16*h)*8] = wv;
        }
      }
      {
        int e = tid >> 6, c = tid & 63, half = c >> 5, cl = c & 31;
        smallw[(e*2 + half)*36 + cl] = tgW2[t*256 + c*4 + e];
      }
      __syncthreads();   // A

      // prefetch fgB^T A-frags for gate step 2 (independent of accT; hides L2 under step 1 + A2)
      U4 afg[4];
      {
        const u16* fgbp = pk + OFF_FGB + (t*16 + wid*4)*512 + lane*8;
        #pragma unroll
        for (int mt4 = 0; mt4 < 4; ++mt4)
          afg[mt4].u = *(const uint4*)(fgbp + mt4*512);
      }

      // ---------- gate step 1 (waves 0,1): accT(8x32) = fgA^T @ cm_pre^T ----------
      if (wid < 2) {
        f32x4 d1 = fz;
        const u16* ap = pk + OFF_FGA + (t*8)*512 + lane*8;
        #pragma unroll
        for (int kt = 0; kt < 8; ++kt) {
          bf16x8 af = ld_frag(ap + kt*512);
          bf16x8 bf = ld_frag(&cmfrag[((wid*8 + kt)*64 + lane)*8]);
          d1 = mfma16(af, bf, d1);
        }
        if (rl < 8) {      // ranks 0-7 live in lane groups 0,1
          #pragma unroll
          for (int rr = 0; rr < 4; ++rr)
            accT[(rl + rr)*34 + wid*16 + l15] = d1[rr];
        }
      }
      __syncthreads();   // A2

      // ---------- gate step 2 (all waves): logitsT = fgB^T @ accT ; gate = 2*sigmoid -> gateT ----------
      {
        // build B-frags (K=32, only k<8 nonzero -> lane group 0 holds data)
        U4 b0u, b1u;
        if (lane < 16) {
          float v0[8], v1[8];
          #pragma unroll
          for (int i = 0; i < 8; ++i) {
            v0[i] = accT[i*34 + l15];
            v1[i] = accT[i*34 + 16 + l15];
          }
          b0u.u.x = f2bf2(v0[0], v0[1]); b0u.u.y = f2bf2(v0[2], v0[3]);
          b0u.u.z = f2bf2(v0[4], v0[5]); b0u.u.w = f2bf2(v0[6], v0[7]);
          b1u.u.x = f2bf2(v1[0], v1[1]); b1u.u.y = f2bf2(v1[2], v1[3]);
          b1u.u.z = f2bf2(v1[4], v1[5]); b1u.u.w = f2bf2(v1[6], v1[7]);
        } else {
          b0u.u = make_uint4(0, 0, 0, 0);
          b1u.u = make_uint4(0, 0, 0, 0);
        }
        #pragma unroll
        for (int mt4 = 0; mt4 < 4; ++mt4) {
          int mtile = wid*4 + mt4;
          f32x4 d0 = mfma16(afg[mt4].v, b0u.v, fz);
          f32x4 d1 = mfma16(afg[mt4].v, b1u.v, fz);
          int fbase = mtile*16 + rl;
          {
            float g0 = 2.f / (1.f + __expf(-d0[0]));
            float g1 = 2.f / (1.f + __expf(-d0[1]));
            float g2 = 2.f / (1.f + __expf(-d0[2]));
            float g3 = 2.f / (1.f + __expf(-d0[3]));
            int rowc = l15;
            *(u32*)&gateT[rowc*264 + fbase]     = f2bf2(g0, g1);
            *(u32*)&gateT[rowc*264 + fbase + 2] = f2bf2(g2, g3);
          }
          {
            float g0 = 2.f / (1.f + __expf(-d1[0]));
            float g1 = 2.f / (1.f + __expf(-d1[1]));
            float g2 = 2.f / (1.f + __expf(-d1[2]));
            float g3 = 2.f / (1.f + __expf(-d1[3]));
            int rowc = 16 + l15;
            *(u32*)&gateT[rowc*264 + fbase]     = f2bf2(g0, g1);
            *(u32*)&gateT[rowc*264 + fbase + 2] = f2bf2(g2, g3);
          }
        }
      }
      __syncthreads();   // A3

      // ---------- gate apply (in-place on cmfrag); thread (r,q) owns row r, features q*32.. ----------
      {
        const int gbase = r*264 + q*32;
        #pragma unroll
        for (int h = 0; h < 4; ++h) {
          u16* cp = &cmfrag[((mt_r*8 + q)*64 + r15 + 16*h)*8];
          uint4 zv = *(const uint4*)cp;
          uint4 gv = *(const uint4*)&gateT[gbase + h*8];
          uint4 wv;
          wv.x = f2bf2(bflo(zv.x)*bflo(gv.x), bfhi(zv.x)*bfhi(gv.x));
          wv.y = f2bf2(bflo(zv.y)*bflo(gv.y), bfhi(zv.y)*bfhi(gv.y));
          wv.z = f2bf2(bflo(zv.z)*bflo(gv.z), bfhi(zv.z)*bfhi(gv.z));
          wv.w = f2bf2(bflo(zv.w)*bflo(gv.w), bfhi(zv.w)*bfhi(gv.w));
          *(uint4*)cp = wv;
        }
      }
      // prefetch tg_W1 kt0,1 B-frags (consumed right after barrier B)
      const u16* wp_tg = pk + OFF_TG + ((t*4 + wid)*8)*512 + lane*8;
      U4 tgp0, tgp1;
      tgp0.u = *(const uint4*)wp_tg;
      tgp1.u = *(const uint4*)(wp_tg + 512);
      __syncthreads();   // B

      // ---------- task gate layer1: gh = swish(cm @ tg_W1 + b); wave w owns n-tile w ----------
      {
        f32x4 accg[2] = { fz, fz };
        #pragma unroll
        for (int kt = 0; kt < 8; ++kt) {
          bf16x8 bfr = (kt == 0) ? tgp0.v : (kt == 1) ? tgp1.v : ld_frag(wp_tg + kt*512);
          #pragma unroll
          for (int mt = 0; mt < 2; ++mt) {
            bf16x8 afr = ld_frag(&cmfrag[((mt*8 + kt)*64 + lane)*8]);
            accg[mt] = mfma16(afr, bfr, accg[mt]);
          }
        }
        int colg = wid*16 + l15;
        float bias = tgb1[t*64 + colg];
        #pragma unroll
        for (int mt = 0; mt < 2; ++mt)
          #pragma unroll
          for (int rr = 0; rr < 4; ++rr)
            fbuf[(mt*16 + rl + rr)*68 + colg] = swishf(accg[mt][rr] + bias);
      }
      __syncthreads();   // C

      // ---------- task gate layer2 + softmax (lanes q,q+4 split the 64-dim dot) ----------
      {
        int e = q & 3, half = q >> 2;
        float part = 0.f;
        #pragma unroll
        for (int cj = 0; cj < 8; ++cj) {
          float4 g4 = *(const float4*)&fbuf[r*68 + half*32 + cj*4];
          float4 w4 = *(const float4*)&smallw[(e*2 + half)*36 + cj*4];
          part += g4.x*w4.x + g4.y*w4.y + g4.z*w4.z + g4.w*w4.w;
        }
        part += __shfl_xor(part, 4);
        float logit = part + tgb2[t*4 + e];
        float mx = fmaxf(logit, __shfl_xor(logit, 1));
        mx = fmaxf(mx, __shfl_xor(mx, 2));
        float ex = __expf(logit - mx);
        float sm = ex + __shfl_xor(ex, 1);
        sm += __shfl_xor(sm, 2);
        if (q < 4) gwbuf[r*4 + q] = ex / sm;
      }
      // NO barrier: gwbuf's first reader (LN, el=0) is 3 barriers (E1,E2,E3) downstream;
      // GEMM1 writes h1frag (gateT/accT dead since barrier B).

      // ---------- expert loop ----------
      float agg[8];
      #pragma unroll
      for (int c = 0; c < 8; ++c) agg[c] = 0.f;

      #pragma unroll 1
      for (int el = 0; el < 4; ++el) {
        const int ei = (el < 2) ? el : (el + 2*g);

        // GEMM1: cm(32x256) @ W1(256x128); wave owns n-tiles 2w,2w+1
        f32x4 acc1[2][2];
        #pragma unroll
        for (int mt = 0; mt < 2; ++mt) { acc1[mt][0] = fz; acc1[mt][1] = fz; }
        {
          const u16* w1p = pk + ((ei*8 + 2*wid)*8)*512 + lane*8;
          #pragma unroll
          for (int kt = 0; kt < 8; ++kt) {
            bf16x8 b0 = ld_frag(w1p + kt*512);
            bf16x8 b1 = ld_frag(w1p + 4096 + kt*512);
            #pragma unroll
            for (int mt = 0; mt < 2; ++mt) {
              bf16x8 a = ld_frag(&cmfrag[((mt*8 + kt)*64 + lane)*8]);
              acc1[mt][0] = mfma16(a, b0, acc1[mt][0]);
              acc1[mt][1] = mfma16(a, b1, acc1[mt][1]);
            }
          }
        }
        // prefetch W2 kt0,1 B-frags (consumed right after barrier E1)
        const u16* w2p = pk + OFF_W2 + ((ei*4 + wid)*4)*512 + lane*8;
        U4 w2f0, w2f1;
        w2f0.u = *(const uint4*)w2p;
        w2f1.u = *(const uint4*)(w2p + 512);
        #pragma unroll
        for (int nn = 0; nn < 2; ++nn) {
          int col = (2*wid + nn)*16 + l15;
          float bias = eb1[ei*128 + col];
          int kt2 = col >> 5, h2 = (col >> 3) & 3, i2 = col & 7;
          #pragma unroll
          for (int mt = 0; mt < 2; ++mt)
            #pragma unroll
            for (int rr = 0; rr < 4; ++rr)
              h1frag[((mt*4 + kt2)*64 + rl + rr + 16*h2)*8 + i2] = f2bf(swishf(acc1[mt][nn][rr] + bias));
        }
        __syncthreads();  // E1

        // GEMM2: h1(32x128) @ W2(128x64); wave owns n-tile w
        f32x4 acc2[2] = { fz, fz };
        {
          #pragma unroll
          for (int kt = 0; kt < 4; ++kt) {
            bf16x8 b0 = (kt == 0) ? w2f0.v : (kt == 1) ? w2f1.v : ld_frag(w2p + kt*512);
            #pragma unroll
            for (int mt = 0; mt < 2; ++mt) {
              bf16x8 a = ld_frag(&h1frag[((mt*4 + kt)*64 + lane)*8]);
              acc2[mt] = mfma16(a, b0, acc2[mt]);
            }
          }
        }
        // prefetch W3 both B-frags (consumed right after barrier E2)
        const u16* w3p = pk + OFF_W3 + ((ei*4 + wid)*2)*512 + lane*8;
        U4 w3f0, w3f1;
        w3f0.u = *(const uint4*)w3p;
        w3f1.u = *(const uint4*)(w3p + 512);
        {
          int col = wid*16 + l15;
          float bias = eb2[ei*64 + col];
          int kt2 = col >> 5, h2 = (col >> 3) & 3, i2 = col & 7;
          #pragma unroll
          for (int mt = 0; mt < 2; ++mt)
            #pragma unroll
            for (int rr = 0; rr < 4; ++rr)
              h2frag[((mt*2 + kt2)*64 + rl + rr + 16*h2)*8 + i2] = f2bf(swishf(acc2[mt][rr] + bias));
        }
        __syncthreads();  // E2

        // GEMM3: h2(32x64) @ W3(64x64) -> e_pre into fbuf (B-frags fully prefetched)
        f32x4 acc3[2] = { fz, fz };
        {
          #pragma unroll
          for (int kt = 0; kt < 2; ++kt) {
            bf16x8 b0 = (kt == 0) ? w3f0.v : w3f1.v;
            #pragma unroll
            for (int mt = 0; mt < 2; ++mt) {
              bf16x8 a = ld_frag(&h2frag[((mt*2 + kt)*64 + lane)*8]);
              acc3[mt] = mfma16(a, b0, acc3[mt]);
            }
          }
        }
        {
          int col = wid*16 + l15;
          float bias = eb3[ei*64 + col];
          #pragma unroll
          for (int mt = 0; mt < 2; ++mt)
            #pragma unroll
            for (int rr = 0; rr < 4; ++rr)
              fbuf[(mt*16 + rl + rr)*68 + col] = acc3[mt][rr] + bias;
        }
        __syncthreads();  // E3

        // LayerNorm + self-gate diag + weighted aggregate (thread (r,q): 8 cols of row r)
        {
          float v[8];
          float4 fa = *(const float4*)&fbuf[r*68 + q*8];
          float4 fb = *(const float4*)&fbuf[r*68 + q*8 + 4];
          v[0]=fa.x; v[1]=fa.y; v[2]=fa.z; v[3]=fa.w;
          v[4]=fb.x; v[5]=fb.y; v[6]=fb.z; v[7]=fb.w;
          float s1 = 0.f;
          #pragma unroll
          for (int c = 0; c < 8; ++c) s1 += v[c];
          s1 += __shfl_xor(s1, 1); s1 += __shfl_xor(s1, 2); s1 += __shfl_xor(s1, 4);
          float mu = s1 * (1.f/64.f);
          float s2 = 0.f;
          #pragma unroll
          for (int c = 0; c < 8; ++c) { float d = v[c] - mu; s2 += d*d; }
          s2 += __shfl_xor(s2, 1); s2 += __shfl_xor(s2, 2); s2 += __shfl_xor(s2, 4);
          float rs = rsqrtf(s2 * (1.f/64.f) + 1e-5f);
          const float* lsp = lns + ei*64 + q*8;
          const float* lbp = lnb + ei*64 + q*8;
          const float* sgp = sgW + (t*64 + q*8)*4 + el;
          float swp = 0.f;
          #pragma unroll
          for (int c = 0; c < 8; ++c) {
            float eh = (v[c] - mu) * rs * lsp[c] + lbp[c];
            v[c] = eh;
            swp += eh * sgp[c*4];
          }
          swp += __shfl_xor(swp, 1); swp += __shfl_xor(swp, 2); swp += __shfl_xor(swp, 4);
          swp += sgb[t*4 + el];
          float fac = swp * gwbuf[r*4 + el];
          #pragma unroll
          for (int c = 0; c < 8; ++c) agg[c] += v[c] * fac;
        }
      }  // expert loop

      // ---------- tower via MFMA: agg(32x64) @ W1(64x64) -> swish -> @ W2(64x32) -> swish -> @ w3 ----------
      {
        uint4 wv;
        wv.x = f2bf2(agg[0], agg[1]);
        wv.y = f2bf2(agg[2], agg[3]);
        wv.z = f2bf2(agg[4], agg[5]);
        wv.w = f2bf2(agg[6], agg[7]);
        *(uint4*)&aggfrag[((mt_r*2 + (q>>2))*64 + r15 + 16*(q&3)) * 8] = wv;
      }
      // prefetch tw_W1 both B-frags (consumed right after barrier F)
      const u16* tw1p = pk + OFF_TW1 + ((t*4 + wid)*2)*512 + lane*8;
      U4 t1f0, t1f1;
      t1f0.u = *(const uint4*)tw1p;
      t1f1.u = *(const uint4*)(tw1p + 512);
      __syncthreads();  // F

      {
        // T1: wave w owns n-tile w of 64 (B-frags fully prefetched)
        f32x4 at1[2] = { fz, fz };
        #pragma unroll
        for (int kt = 0; kt < 2; ++kt) {
          bf16x8 b0 = (kt == 0) ? t1f0.v : t1f1.v;
          #pragma unroll
          for (int mt = 0; mt < 2; ++mt) {
            bf16x8 a = ld_frag(&aggfrag[((mt*2 + kt)*64 + lane)*8]);
            at1[mt] = mfma16(a, b0, at1[mt]);
          }
        }
        int colT = wid*16 + l15;
        float bias = twb1[t*64 + colT];
        int ktT = colT >> 5, hT = (colT >> 3) & 3, iT = colT & 7;
        #pragma unroll
        for (int mt = 0; mt < 2; ++mt)
          #pragma unroll
          for (int rr = 0; rr < 4; ++rr)
            th1frag[((mt*2 + ktT)*64 + rl + rr + 16*hT)*8 + iT] = f2bf(swishf(at1[mt][rr] + bias));
      }
      __syncthreads();  // G

      // T2 + output: wave 0 alone computes both 16-col tiles, reduces, writes out.
      // Waves 1-3 run ahead into next sub's staging (cmfrag/smallw writes) — safe:
      // their next write to region2 (gateT) is behind barriers A+A2, which wave 0
      // joins only after finishing its th1frag reads here.
      if (wid == 0) {
        f32x4 at2[2][2] = { { fz, fz }, { fz, fz } };   // [nt][mt]
        const u16* tw2p = pk + OFF_TW2 + (t*2*2)*512 + lane*8;
        #pragma unroll
        for (int kt = 0; kt < 2; ++kt) {
          bf16x8 b0 = ld_frag(tw2p + kt*512);
          bf16x8 b1 = ld_frag(tw2p + 1024 + kt*512);
          #pragma unroll
          for (int mt = 0; mt < 2; ++mt) {
            bf16x8 a = ld_frag(&th1frag[((mt*2 + kt)*64 + lane)*8]);
            at2[0][mt] = mfma16(a, b0, at2[0][mt]);
            at2[1][mt] = mfma16(a, b1, at2[1][mt]);
          }
        }
        float pxs[8];
        #pragma unroll
        for (int nt = 0; nt < 2; ++nt) {
          int colU = nt*16 + l15;
          float b2  = twb2[t*32 + colU];
          float w3v = twW3[t*32 + colU];
          #pragma unroll
          for (int mt = 0; mt < 2; ++mt)
            #pragma unroll
            for (int rr = 0; rr < 4; ++rr) {
              float val = swishf(at2[nt][mt][rr] + b2) * w3v;
              if (nt == 0) pxs[mt*4 + rr] = val;
              else         pxs[mt*4 + rr] += val;
            }
        }
        #pragma unroll
        for (int k = 0; k < 8; ++k) {
          pxs[k] += __shfl_xor(pxs[k], 1);
          pxs[k] += __shfl_xor(pxs[k], 2);
          pxs[k] += __shfl_xor(pxs[k], 4);
          pxs[k] += __shfl_xor(pxs[k], 8);
        }
        if (l15 == 0) {
          float b3 = twb3[t];
          #pragma unroll
          for (int mt = 0; mt < 2; ++mt)
            #pragma unroll
            for (int rr = 0; rr < 4; ++rr) {
              int row = mt*16 + rl + rr;
              float x = pxs[mt*4 + rr] + b3;
              out[(size_t)(rowBase + row)*4 + t] = 1.f / (1.f + __expf(-x));
            }
        }
      }
      // no barrier H: see comment above.
    }
  }
}

extern "C" void kernel_launch(void* const* d_in, const int* in_sizes, int n_in,
                              void* d_out, int out_size, void* d_ws, size_t ws_size,
                              hipStream_t stream)
{
  (void)in_sizes; (void)n_in; (void)out_size; (void)ws_size;
  const float* zs   = (const float*)d_in[0];
  const float* zg0  = (const float*)d_in[1];
  const float* zg1  = (const float*)d_in[2];
  // d_in[3] = v : unused by the reference
  const float* eW1  = (const float*)d_in[4];
  const float* eb1  = (const float*)d_in[5];
  const float* eW2  = (const float*)d_in[6];
  const float* eb2  = (const float*)d_in[7];
  const float* eW3  = (const float*)d_in[8];
  const float* eb3  = (const float*)d_in[9];
  const float* lns  = (const float*)d_in[10];
  const float* lnb  = (const float*)d_in[11];
  const float* fgA  = (const float*)d_in[12];
  const float* fgB  = (const float*)d_in[13];
  const float* tgW1 = (const float*)d_in[14];
  const float* tgb1 = (const float*)d_in[15];
  const float* tgW2 = (const float*)d_in[16];
  const float* tgb2 = (const float*)d_in[17];
  const float* sgW  = (const float*)d_in[18];
  const float* sgb  = (const float*)d_in[19];
  const float* twW1 = (const float*)d_in[20];
  const float* twb1 = (const float*)d_in[21];
  const float* twW2 = (const float*)d_in[22];
  const float* twb2 = (const float*)d_in[23];
  const float* twW3 = (const float*)d_in[24];
  const float* twb3 = (const float*)d_in[25];

  u16* pkw = (u16*)d_ws;          // needs 819200 B
  float* outp = (float*)d_out;

  prep_pack<<<(NPACK + 255)/256, 256, 0, stream>>>(eW1, eW2, eW3, tgW1, twW1, twW2, fgA, fgB, pkw);
  home_main<<<65536/32, 256, 0, stream>>>(zs, zg0, zg1, tgW2, tgb1, tgb2,
      eb1, eb2, eb3, lns, lnb, sgW, sgb, twb1, twb2, twW3, twb3,
      pkw, outp);
}

// Round 11
// 345.901 us; speedup vs baseline: 2.2413x; 1.1424x over previous
//
#include <hip/hip_runtime.h>

typedef unsigned short u16;
typedef unsigned int   u32;
typedef __bf16 bf16x8 __attribute__((ext_vector_type(8)));
typedef float  f32x4  __attribute__((ext_vector_type(4)));

// packed-weight regions (bf16 elements) in d_ws
#define OFF_W2  196608
#define OFF_W3  245760
#define OFF_TG  270336
#define OFF_TW1 335872
#define OFF_TW2 352256
#define OFF_FGA 360448
#define OFF_FGB 376832
#define NPACK   409600

// native f32->bf16 (RNE): v_cvt_pk_bf16_f32
__device__ __forceinline__ u16 f2bf(float f) {
  union { __bf16 b; u16 u; } cv;
  cv.b = (__bf16)f;
  return cv.u;
}
__device__ __forceinline__ u32 f2bf2(float lo, float hi) {
  return (u32)f2bf(lo) | ((u32)f2bf(hi) << 16);
}
__device__ __forceinline__ float bf2f(u16 s) { return __uint_as_float(((u32)s) << 16); }
__device__ __forceinline__ float bflo(u32 p) { return __uint_as_float(p << 16); }
__device__ __forceinline__ float bfhi(u32 p) { return __uint_as_float(p & 0xffff0000u); }

union U4 { uint4 u; bf16x8 v; };
__device__ __forceinline__ bf16x8 ld_frag(const u16* p) {
  U4 t; t.u = *(const uint4*)p; return t.v;
}
__device__ __forceinline__ f32x4 mfma16(bf16x8 a, bf16x8 b, f32x4 c) {
  return __builtin_amdgcn_mfma_f32_16x16x32_bf16(a, b, c, 0, 0, 0);
}
__device__ __forceinline__ float swishf(float x) { return x / (1.f + __expf(-x)); }
__device__ __forceinline__ float sig2(float x) { return 2.f / (1.f + __expf(-x)); }

// ---------------- weight repack: f32 row-major -> bf16 fragment order (unchanged) ----------------
__global__ __launch_bounds__(256) void prep_pack(
    const float* __restrict__ eW1, const float* __restrict__ eW2,
    const float* __restrict__ eW3, const float* __restrict__ tgW1,
    const float* __restrict__ twW1, const float* __restrict__ twW2,
    const float* __restrict__ fgA, const float* __restrict__ fgB,
    u16* __restrict__ pk)
{
  int idx = blockIdx.x * 256 + threadIdx.x;
  if (idx >= NPACK) return;
  float v;
  if (idx < OFF_W2) {                 // exp_W1: [6][nt:8][kt:8][64][8]
    int i = idx & 7, lane = (idx >> 3) & 63, kt = (idx >> 9) & 7, nt = (idx >> 12) & 7, e = idx >> 15;
    int k = kt*32 + (lane>>4)*8 + i, n = nt*16 + (lane & 15);
    v = eW1[(e*256 + k)*128 + n];
  } else if (idx < OFF_W3) {          // exp_W2: [6][nt:4][kt:4][64][8]
    int j = idx - OFF_W2;
    int i = j & 7, lane = (j >> 3) & 63, kt = (j >> 9) & 3, nt = (j >> 11) & 3, e = j >> 13;
    int k = kt*32 + (lane>>4)*8 + i, n = nt*16 + (lane & 15);
    v = eW2[(e*128 + k)*64 + n];
  } else if (idx < OFF_TG) {          // exp_W3: [6][nt:4][kt:2][64][8]
    int j = idx - OFF_W3;
    int i = j & 7, lane = (j >> 3) & 63, kt = (j >> 9) & 1, nt = (j >> 10) & 3, e = j >> 12;
    int k = kt*32 + (lane>>4)*8 + i, n = nt*16 + (lane & 15);
    v = eW3[(e*64 + k)*64 + n];
  } else if (idx < OFF_TW1) {         // tg_W1: [4][nt:4][kt:8][64][8]
    int j = idx - OFF_TG;
    int i = j & 7, lane = (j >> 3) & 63, kt = (j >> 9) & 7, nt = (j >> 12) & 3, t = j >> 14;
    int k = kt*32 + (lane>>4)*8 + i, n = nt*16 + (lane & 15);
    v = tgW1[(t*256 + k)*64 + n];
  } else if (idx < OFF_TW2) {         // tw_W1: [4][nt:4][kt:2][64][8]
    int j = idx - OFF_TW1;
    int i = j & 7, lane = (j >> 3) & 63, kt = (j >> 9) & 1, nt = (j >> 10) & 3, t = j >> 12;
    int k = kt*32 + (lane>>4)*8 + i, n = nt*16 + (lane & 15);
    v = twW1[(t*64 + k)*64 + n];
  } else if (idx < OFF_FGA) {         // tw_W2: [4][nt:2][kt:2][64][8]
    int j = idx - OFF_TW2;
    int i = j & 7, lane = (j >> 3) & 63, kt = (j >> 9) & 1, nt = (j >> 10) & 1, t = j >> 11;
    int k = kt*32 + (lane>>4)*8 + i, n = nt*16 + (lane & 15);
    v = twW2[(t*64 + k)*32 + n];
  } else if (idx < OFF_FGB) {         // fgA^T A-frags: [4][kt:8][64][8]
    int j = idx - OFF_FGA;
    int i = j & 7, lane = (j >> 3) & 63, kt = (j >> 9) & 7, t = j >> 12;
    int m = lane & 15, k = kt*32 + (lane>>4)*8 + i;
    v = (m < 8) ? fgA[(t*256 + k)*8 + m] : 0.f;
  } else {                            // fgB^T A-frags: [4][mtile:16][64][8]
    int j = idx - OFF_FGB;
    int i = j & 7, lane = (j >> 3) & 63, mtl = (j >> 9) & 15, t = j >> 13;
    int m = mtl*16 + (lane & 15), kr = (lane>>4)*8 + i;
    v = (kr < 8) ? fgB[t*2048 + kr*256 + m] : 0.f;
  }
  pk[idx] = f2bf(v);
}

// ---------------- fused main kernel: 32 batch rows/block, M=64 task-pair-batched expert chain ----------------
// r11: tasks t=2g,2g+1 share their 4 experts -> run expert GEMMs ONCE at M=64
// ([t0-gated cm; t1-gated cm]) instead of twice at M=32: halves barrier-phases and
// weight fetches per unit work (r10 diagnosis: phase-count bound, ~33K cy per 17-phase sub).
// Gate-apply fused into step2 epilogue (in-place b64 RMW on cmfrag) deletes gateT + 1 barrier.
// VGPR discipline (r5/r7 lessons): GEMM1 in 2 passes over task halves (acc=16 regs),
// launch_bounds(256,3) -> 84-reg budget. LDS 78.3 KB -> 2 blocks/CU.
__global__ __launch_bounds__(256, 3) void home_main(
    const float* __restrict__ zs, const float* __restrict__ zg0, const float* __restrict__ zg1,
    const float* __restrict__ tgW2, const float* __restrict__ tgb1, const float* __restrict__ tgb2,
    const float* __restrict__ eb1, const float* __restrict__ eb2, const float* __restrict__ eb3,
    const float* __restrict__ lns, const float* __restrict__ lnb,
    const float* __restrict__ sgW, const float* __restrict__ sgb,
    const float* __restrict__ twb1, const float* __restrict__ twb2,
    const float* __restrict__ twW3, const float* __restrict__ twb3,
    const u16* __restrict__ pk, float* __restrict__ out)
{
  __shared__ __align__(16) u16   cmfrag[4*8*64*8];   // 32768 B  [mt4][kt8][64][8]: mt0,1=t0 copy; mt2,3=t1 copy
  __shared__ __align__(16) u16   h1frag[4*4*64*8];   // 16384 B  [mt4][kt4][64][8]; alias accT f32[2][8][34]
  __shared__ __align__(16) u16   h2frag[4*2*64*8];   //  8192 B  [mt4][kt2][64][8]; alias aggfrag [8][64][8]
  __shared__ __align__(16) float fbuf[2*32*68];      // 17408 B  gh / e_pre per task; alias th1frag u16[2][2048]
  __shared__ __align__(16) float gwbuf[256];         //  1024 B  [2][32][4] softmax gate weights
  __shared__ __align__(16) float smallw[640];        //  2560 B  [2][320] tg_W2^T swizzled

  float* accT    = (float*)h1frag;   // [2][8][34] (gate phase only; dead before h1frag written)
  u16*   aggfrag = h2frag;           // [8 tiles][64][8]
  u16*   th1frag = (u16*)fbuf;       // [2][2048]

  const int tid  = threadIdx.x;
  const int lane = tid & 63;
  const int wid  = tid >> 6;       // wave 0..3
  const int r    = tid >> 3;       // row 0..31 (staging / softmax)
  const int q    = tid & 7;        // eighth of the 256-d feature
  const int rowBase = blockIdx.x * 32;
  const int mt_r = r >> 4, r15 = r & 15;
  const int rl   = (lane >> 4) * 4;   // C-layout row offset
  const int l15  = lane & 15;
  const int tkw  = wid >> 1;          // wave's task (0/1 within pair)
  const int chw  = wid & 1;           // wave's half-role
  const f32x4 fz = {0.f, 0.f, 0.f, 0.f};

  #pragma unroll 1
  for (int pair = 0; pair < 2; ++pair) {
    const int g = pair;
    const int tg0 = g*2 + tkw;       // wave's global task id

    // ---------- stage cm_pre (bf16) into BOTH task copies + tg_W2 for both tasks ----------
    {
      const float* zsrc = (q < 4)
        ? (zs + (size_t)(rowBase + r) * 128 + q * 32)
        : ((pair ? zg1 : zg0) + (size_t)(rowBase + r) * 128 + (q - 4) * 32);
      #pragma unroll
      for (int h = 0; h < 4; ++h) {
        float4 a = ((const float4*)zsrc)[2*h], b4 = ((const float4*)zsrc)[2*h+1];
        uint4 wv;
        wv.x = f2bf2(a.x, a.y);
        wv.y = f2bf2(a.z, a.w);
        wv.z = f2bf2(b4.x, b4.y);
        wv.w = f2bf2(b4.z, b4.w);
        *(uint4*)&cmfrag[((mt_r*8 + q)*64 + r15 + 16*h)*8] = wv;
        *(uint4*)&cmfrag[(((mt_r+2)*8 + q)*64 + r15 + 16*h)*8] = wv;
      }
    }
    #pragma unroll
    for (int tk = 0; tk < 2; ++tk) {
      int e = tid >> 6, c = tid & 63, half = c >> 5, cl = c & 31;
      smallw[tk*320 + (e*2 + half)*36 + cl] = tgW2[(g*2+tk)*256 + c*4 + e];
    }
    __syncthreads();   // A

    // prefetch fgB^T A-frags (first 4 of this wave's 8 mtiles)
    const u16* fgbp = pk + OFF_FGB + (tg0*16 + chw*8)*512 + lane*8;
    U4 afg[4];
    #pragma unroll
    for (int m4 = 0; m4 < 4; ++m4) afg[m4].u = *(const uint4*)(fgbp + m4*512);

    // ---------- gate step 1 (all 4 waves): accT[tk](8x32) = fgA^T @ cm_pre^T ----------
    {
      f32x4 d1 = fz;
      const u16* ap = pk + OFF_FGA + (tg0*8)*512 + lane*8;
      #pragma unroll
      for (int kt = 0; kt < 8; ++kt) {
        bf16x8 af = ld_frag(ap + kt*512);
        bf16x8 bf = ld_frag(&cmfrag[(((2*tkw + chw)*8 + kt)*64 + lane)*8]);
        d1 = mfma16(af, bf, d1);
      }
      if (rl < 8) {
        #pragma unroll
        for (int rr = 0; rr < 4; ++rr)
          accT[tkw*272 + (rl + rr)*34 + chw*16 + l15] = d1[rr];
      }
    }
    __syncthreads();   // A2

    // ---------- gate step 2 + in-place apply: logits = fgB^T @ accT; cm *= 2*sigmoid ----------
    {
      U4 b0u, b1u;
      if (lane < 16) {
        float v0[8], v1[8];
        #pragma unroll
        for (int i = 0; i < 8; ++i) {
          v0[i] = accT[tkw*272 + i*34 + l15];
          v1[i] = accT[tkw*272 + i*34 + 16 + l15];
        }
        b0u.u.x = f2bf2(v0[0], v0[1]); b0u.u.y = f2bf2(v0[2], v0[3]);
        b0u.u.z = f2bf2(v0[4], v0[5]); b0u.u.w = f2bf2(v0[6], v0[7]);
        b1u.u.x = f2bf2(v1[0], v1[1]); b1u.u.y = f2bf2(v1[2], v1[3]);
        b1u.u.z = f2bf2(v1[4], v1[5]); b1u.u.w = f2bf2(v1[6], v1[7]);
      } else {
        b0u.u = make_uint4(0, 0, 0, 0);
        b1u.u = make_uint4(0, 0, 0, 0);
      }
      const int i0 = rl & 7;              // 0 or 4
      const int hlo = rl >> 3;            // 0 or 1
      #pragma unroll
      for (int m8 = 0; m8 < 8; ++m8) {
        int mtile = chw*8 + m8;
        bf16x8 af = (m8 < 4) ? afg[m8].v : ld_frag(fgbp + m8*512);
        f32x4 d0 = mfma16(af, b0u.v, fz);
        f32x4 d1 = mfma16(af, b1u.v, fz);
        int ktc = mtile >> 1;
        int hh  = (mtile & 1)*2 + hlo;
        // rows 0-15 of this task -> mt = 2*tkw
        {
          u16* cp = &cmfrag[(((2*tkw)*8 + ktc)*64 + l15 + 16*hh)*8 + i0];
          u32 za = ((u32*)cp)[0], zb = ((u32*)cp)[1];
          float g0 = sig2(d0[0]), g1 = sig2(d0[1]), g2 = sig2(d0[2]), g3 = sig2(d0[3]);
          ((u32*)cp)[0] = f2bf2(bflo(za)*g0, bfhi(za)*g1);
          ((u32*)cp)[1] = f2bf2(bflo(zb)*g2, bfhi(zb)*g3);
        }
        // rows 16-31 -> mt = 2*tkw+1
        {
          u16* cp = &cmfrag[(((2*tkw + 1)*8 + ktc)*64 + l15 + 16*hh)*8 + i0];
          u32 za = ((u32*)cp)[0], zb = ((u32*)cp)[1];
          float g0 = sig2(d1[0]), g1 = sig2(d1[1]), g2 = sig2(d1[2]), g3 = sig2(d1[3]);
          ((u32*)cp)[0] = f2bf2(bflo(za)*g0, bfhi(za)*g1);
          ((u32*)cp)[1] = f2bf2(bflo(zb)*g2, bfhi(zb)*g3);
        }
      }
    }
    // prefetch tg_W1 kt0 for both of this wave's n-tiles (consumed right after A3)
    const u16* wp_tg = pk + OFF_TG + ((tg0*4 + chw*2)*8)*512 + lane*8;
    U4 tgp0, tgp1;
    tgp0.u = *(const uint4*)wp_tg;
    tgp1.u = *(const uint4*)(wp_tg + 4096);
    __syncthreads();   // A3

    // ---------- task gate layer1: wave (tk=wid>>1) computes n-tiles chw*2, chw*2+1 ----------
    {
      f32x4 accg[2][2] = { { fz, fz }, { fz, fz } };   // [mtl][nt2]
      #pragma unroll
      for (int kt = 0; kt < 8; ++kt) {
        bf16x8 b0 = (kt == 0) ? tgp0.v : ld_frag(wp_tg + kt*512);
        bf16x8 b1 = (kt == 0) ? tgp1.v : ld_frag(wp_tg + 4096 + kt*512);
        #pragma unroll
        for (int mtl = 0; mtl < 2; ++mtl) {
          bf16x8 a = ld_frag(&cmfrag[(((2*tkw + mtl)*8 + kt)*64 + lane)*8]);
          accg[mtl][0] = mfma16(a, b0, accg[mtl][0]);
          accg[mtl][1] = mfma16(a, b1, accg[mtl][1]);
        }
      }
      #pragma unroll
      for (int nt2 = 0; nt2 < 2; ++nt2) {
        int colg = (chw*2 + nt2)*16 + l15;
        float bias = tgb1[tg0*64 + colg];
        #pragma unroll
        for (int mtl = 0; mtl < 2; ++mtl)
          #pragma unroll
          for (int rr = 0; rr < 4; ++rr)
            fbuf[(tkw*32 + mtl*16 + rl + rr)*68 + colg] = swishf(accg[mtl][nt2][rr] + bias);
      }
    }
    __syncthreads();   // C

    // ---------- task gate layer2 + softmax, both tasks ----------
    #pragma unroll
    for (int tk = 0; tk < 2; ++tk) {
      int e = q & 3, half = q >> 2;
      float part = 0.f;
      #pragma unroll
      for (int cj = 0; cj < 8; ++cj) {
        float4 g4 = *(const float4*)&fbuf[(tk*32 + r)*68 + half*32 + cj*4];
        float4 w4 = *(const float4*)&smallw[tk*320 + (e*2 + half)*36 + cj*4];
        part += g4.x*w4.x + g4.y*w4.y + g4.z*w4.z + g4.w*w4.w;
      }
      part += __shfl_xor(part, 4);
      float logit = part + tgb2[(g*2+tk)*4 + e];
      float mx = fmaxf(logit, __shfl_xor(logit, 1));
      mx = fmaxf(mx, __shfl_xor(mx, 2));
      float ex = __expf(logit - mx);
      float sm = ex + __shfl_xor(ex, 1);
      sm += __shfl_xor(sm, 2);
      if (q < 4) gwbuf[tk*128 + r*4 + q] = ex / sm;
    }
    // NO barrier: gwbuf first read (LN el0) is >=3 barriers downstream; GEMM1 writes h1frag
    // (accT alias dead since A3).

    // ---------- expert loop: M=64 (both tasks) ----------
    float agg[16];
    #pragma unroll
    for (int c = 0; c < 16; ++c) agg[c] = 0.f;

    const int mL  = tid >> 2;        // LN row 0..63
    const int qc  = tid & 3;         // LN col quarter (16 cols)
    const int tkL = mL >> 5, mrL = mL & 31;

    #pragma unroll 1
    for (int el = 0; el < 4; ++el) {
      const int ei = (el < 2) ? el : (el + 2*g);

      // GEMM1: cm(64x256) @ W1(256x128); wave owns n-tiles 2w,2w+1; 2 passes over task halves
      const u16* w1p = pk + ((ei*8 + 2*wid)*8)*512 + lane*8;
      #pragma unroll 1
      for (int pass = 0; pass < 2; ++pass) {
        f32x4 acc1[2][2] = { { fz, fz }, { fz, fz } };   // [mtl][nn]
        #pragma unroll
        for (int kt = 0; kt < 8; ++kt) {
          bf16x8 b0 = ld_frag(w1p + kt*512);
          bf16x8 b1 = ld_frag(w1p + 4096 + kt*512);
          #pragma unroll
          for (int mtl = 0; mtl < 2; ++mtl) {
            bf16x8 a = ld_frag(&cmfrag[(((pass*2 + mtl)*8 + kt)*64 + lane)*8]);
            acc1[mtl][0] = mfma16(a, b0, acc1[mtl][0]);
            acc1[mtl][1] = mfma16(a, b1, acc1[mtl][1]);
          }
        }
        #pragma unroll
        for (int nn = 0; nn < 2; ++nn) {
          int col = (2*wid + nn)*16 + l15;
          float bias = eb1[ei*128 + col];
          int kt2 = col >> 5, h2 = (col >> 3) & 3, i2 = col & 7;
          #pragma unroll
          for (int mtl = 0; mtl < 2; ++mtl)
            #pragma unroll
            for (int rr = 0; rr < 4; ++rr)
              h1frag[(((pass*2 + mtl)*4 + kt2)*64 + rl + rr + 16*h2)*8 + i2] =
                  f2bf(swishf(acc1[mtl][nn][rr] + bias));
        }
      }
      // prefetch W2 kt0,1 (consumed right after E1)
      const u16* w2p = pk + OFF_W2 + ((ei*4 + wid)*4)*512 + lane*8;
      U4 w2f0, w2f1;
      w2f0.u = *(const uint4*)w2p;
      w2f1.u = *(const uint4*)(w2p + 512);
      __syncthreads();  // E1

      // GEMM2: h1(64x128) @ W2(128x64); wave owns n-tile w
      f32x4 acc2[4] = { fz, fz, fz, fz };
      #pragma unroll
      for (int kt = 0; kt < 4; ++kt) {
        bf16x8 b0 = (kt == 0) ? w2f0.v : (kt == 1) ? w2f1.v : ld_frag(w2p + kt*512);
        #pragma unroll
        for (int mt = 0; mt < 4; ++mt) {
          bf16x8 a = ld_frag(&h1frag[((mt*4 + kt)*64 + lane)*8]);
          acc2[mt] = mfma16(a, b0, acc2[mt]);
        }
      }
      // prefetch W3 both frags (consumed right after E2)
      const u16* w3p = pk + OFF_W3 + ((ei*4 + wid)*2)*512 + lane*8;
      U4 w3f0, w3f1;
      w3f0.u = *(const uint4*)w3p;
      w3f1.u = *(const uint4*)(w3p + 512);
      {
        int col = wid*16 + l15;
        float bias = eb2[ei*64 + col];
        int kt2 = col >> 5, h2 = (col >> 3) & 3, i2 = col & 7;
        #pragma unroll
        for (int mt = 0; mt < 4; ++mt)
          #pragma unroll
          for (int rr = 0; rr < 4; ++rr)
            h2frag[((mt*2 + kt2)*64 + rl + rr + 16*h2)*8 + i2] = f2bf(swishf(acc2[mt][rr] + bias));
      }
      __syncthreads();  // E2

      // GEMM3: h2(64x64) @ W3(64x64) -> e_pre into fbuf (per-task halves)
      f32x4 acc3[4] = { fz, fz, fz, fz };
      #pragma unroll
      for (int kt = 0; kt < 2; ++kt) {
        bf16x8 b0 = (kt == 0) ? w3f0.v : w3f1.v;
        #pragma unroll
        for (int mt = 0; mt < 4; ++mt) {
          bf16x8 a = ld_frag(&h2frag[((mt*2 + kt)*64 + lane)*8]);
          acc3[mt] = mfma16(a, b0, acc3[mt]);
        }
      }
      {
        int col = wid*16 + l15;
        float bias = eb3[ei*64 + col];
        #pragma unroll
        for (int mt = 0; mt < 4; ++mt)
          #pragma unroll
          for (int rr = 0; rr < 4; ++rr) {
            int m = mt*16 + rl + rr;
            fbuf[((m >> 5)*32 + (m & 31))*68 + col] = acc3[mt][rr] + bias;
          }
      }
      __syncthreads();  // E3

      // LayerNorm + self-gate diag + weighted aggregate (thread: row mL, 16 cols qc*16..)
      {
        float v[16];
        #pragma unroll
        for (int cc = 0; cc < 4; ++cc) {
          float4 f = *(const float4*)&fbuf[(tkL*32 + mrL)*68 + qc*16 + cc*4];
          v[cc*4+0] = f.x; v[cc*4+1] = f.y; v[cc*4+2] = f.z; v[cc*4+3] = f.w;
        }
        float s1 = 0.f;
        #pragma unroll
        for (int c = 0; c < 16; ++c) s1 += v[c];
        s1 += __shfl_xor(s1, 1); s1 += __shfl_xor(s1, 2);
        float mu = s1 * (1.f/64.f);
        float s2 = 0.f;
        #pragma unroll
        for (int c = 0; c < 16; ++c) { float d = v[c] - mu; s2 += d*d; }
        s2 += __shfl_xor(s2, 1); s2 += __shfl_xor(s2, 2);
        float rs = rsqrtf(s2 * (1.f/64.f) + 1e-5f);
        const int tgL = g*2 + tkL;
        const float* lsp = lns + ei*64 + qc*16;
        const float* lbp = lnb + ei*64 + qc*16;
        const float* sgp = sgW + (tgL*64 + qc*16)*4 + el;
        float swp = 0.f;
        #pragma unroll
        for (int c = 0; c < 16; ++c) {
          float eh = (v[c] - mu) * rs * lsp[c] + lbp[c];
          v[c] = eh;
          swp += eh * sgp[c*4];
        }
        swp += __shfl_xor(swp, 1); swp += __shfl_xor(swp, 2);
        swp += sgb[tgL*4 + el];
        float fac = swp * gwbuf[tkL*128 + mrL*4 + el];
        #pragma unroll
        for (int c = 0; c < 16; ++c) agg[c] += v[c] * fac;
      }
      // no trailing barrier: next GEMM1 writes h1frag (disjoint from fbuf/gwbuf); E1 orders.
    }  // expert loop

    // ---------- tower: agg(64x64) -> T1 (per task 32x64) -> T2 (32x32) -> out ----------
    {
      // write agg as A-frags: thread row mL, feats qc*16+0..15 (2 b128)
      #pragma unroll
      for (int jh = 0; jh < 2; ++jh) {
        uint4 wv;
        wv.x = f2bf2(agg[jh*8+0], agg[jh*8+1]);
        wv.y = f2bf2(agg[jh*8+2], agg[jh*8+3]);
        wv.z = f2bf2(agg[jh*8+4], agg[jh*8+5]);
        wv.w = f2bf2(agg[jh*8+6], agg[jh*8+7]);
        int tile = (mL >> 4)*2 + (qc >> 1);
        int slot = (mL & 15) + 16*((qc & 1)*2 + jh);
        *(uint4*)&aggfrag[(tile*64 + slot)*8] = wv;
      }
    }
    // prefetch tw_W1 kt0 for both of this wave's n-tiles
    const u16* tw1b = pk + OFF_TW1 + ((tg0*4 + chw*2)*2)*512 + lane*8;
    U4 t1f0, t1f1;
    t1f0.u = *(const uint4*)tw1b;
    t1f1.u = *(const uint4*)(tw1b + 1024);
    __syncthreads();  // F

    // T1: wave (task tkw) computes n-tiles chw*2, chw*2+1 of its task's 64 cols
    {
      f32x4 at1[2][2] = { { fz, fz }, { fz, fz } };   // [mtl][nt2]
      #pragma unroll
      for (int kt = 0; kt < 2; ++kt) {
        bf16x8 b0 = (kt == 0) ? t1f0.v : ld_frag(tw1b + kt*512);
        bf16x8 b1 = (kt == 0) ? t1f1.v : ld_frag(tw1b + 1024 + kt*512);
        #pragma unroll
        for (int mtl = 0; mtl < 2; ++mtl) {
          bf16x8 a = ld_frag(&aggfrag[(((2*tkw + mtl)*2 + kt)*64 + lane)*8]);
          at1[mtl][0] = mfma16(a, b0, at1[mtl][0]);
          at1[mtl][1] = mfma16(a, b1, at1[mtl][1]);
        }
      }
      #pragma unroll
      for (int nt2 = 0; nt2 < 2; ++nt2) {
        int colT = (chw*2 + nt2)*16 + l15;
        float bias = twb1[tg0*64 + colT];
        int ktT = colT >> 5, hT = (colT >> 3) & 3, iT = colT & 7;
        #pragma unroll
        for (int mtl = 0; mtl < 2; ++mtl)
          #pragma unroll
          for (int rr = 0; rr < 4; ++rr)
            th1frag[tkw*2048 + ((mtl*2 + ktT)*64 + rl + rr + 16*hT)*8 + iT] =
                f2bf(swishf(at1[mtl][nt2][rr] + bias));
      }
    }
    __syncthreads();  // G

    // T2 + output: wave w<2 handles task w entirely (both 16-col tiles), writes out.
    if (wid < 2) {
      const int tg = g*2 + wid;
      f32x4 at2[2][2] = { { fz, fz }, { fz, fz } };   // [nt][mtl]
      const u16* tw2p = pk + OFF_TW2 + (tg*2*2)*512 + lane*8;
      #pragma unroll
      for (int kt = 0; kt < 2; ++kt) {
        bf16x8 b0 = ld_frag(tw2p + kt*512);
        bf16x8 b1 = ld_frag(tw2p + 1024 + kt*512);
        #pragma unroll
        for (int mtl = 0; mtl < 2; ++mtl) {
          bf16x8 a = ld_frag(&th1frag[wid*2048 + ((mtl*2 + kt)*64 + lane)*8]);
          at2[0][mtl] = mfma16(a, b0, at2[0][mtl]);
          at2[1][mtl] = mfma16(a, b1, at2[1][mtl]);
        }
      }
      float pxs[8];
      #pragma unroll
      for (int nt = 0; nt < 2; ++nt) {
        int colU = nt*16 + l15;
        float b2  = twb2[tg*32 + colU];
        float w3v = twW3[tg*32 + colU];
        #pragma unroll
        for (int mtl = 0; mtl < 2; ++mtl)
          #pragma unroll
          for (int rr = 0; rr < 4; ++rr) {
            float val = swishf(at2[nt][mtl][rr] + b2) * w3v;
            if (nt == 0) pxs[mtl*4 + rr] = val;
            else         pxs[mtl*4 + rr] += val;
          }
      }
      #pragma unroll
      for (int k = 0; k < 8; ++k) {
        pxs[k] += __shfl_xor(pxs[k], 1);
        pxs[k] += __shfl_xor(pxs[k], 2);
        pxs[k] += __shfl_xor(pxs[k], 4);
        pxs[k] += __shfl_xor(pxs[k], 8);
      }
      if (l15 == 0) {
        float b3 = twb3[tg];
        #pragma unroll
        for (int mtl = 0; mtl < 2; ++mtl)
          #pragma unroll
          for (int rr = 0; rr < 4; ++rr) {
            int row = mtl*16 + rl + rr;
            float x = pxs[mtl*4 + rr] + b3;
            out[(size_t)(rowBase + row)*4 + tg] = 1.f / (1.f + __expf(-x));
          }
      }
    }
    // no trailing barrier: next pair's staging writes cmfrag/smallw whose last readers
    // (GEMM1 el3 / softmax) are many barriers back; th1frag (fbuf) readers here are
    // waves 0,1 only, and next writes to that region (tg1 epilogue) are behind A/A2/A3.
  }
}

extern "C" void kernel_launch(void* const* d_in, const int* in_sizes, int n_in,
                              void* d_out, int out_size, void* d_ws, size_t ws_size,
                              hipStream_t stream)
{
  (void)in_sizes; (void)n_in; (void)out_size; (void)ws_size;
  const float* zs   = (const float*)d_in[0];
  const float* zg0  = (const float*)d_in[1];
  const float* zg1  = (const float*)d_in[2];
  // d_in[3] = v : unused by the reference
  const float* eW1  = (const float*)d_in[4];
  const float* eb1  = (const float*)d_in[5];
  const float* eW2  = (const float*)d_in[6];
  const float* eb2  = (const float*)d_in[7];
  const float* eW3  = (const float*)d_in[8];
  const float* eb3  = (const float*)d_in[9];
  const float* lns  = (const float*)d_in[10];
  const float* lnb  = (const float*)d_in[11];
  const float* fgA  = (const float*)d_in[12];
  const float* fgB  = (const float*)d_in[13];
  const float* tgW1 = (const float*)d_in[14];
  const float* tgb1 = (const float*)d_in[15];
  const float* tgW2 = (const float*)d_in[16];
  const float* tgb2 = (const float*)d_in[17];
  const float* sgW  = (const float*)d_in[18];
  const float* sgb  = (const float*)d_in[19];
  const float* twW1 = (const float*)d_in[20];
  const float* twb1 = (const float*)d_in[21];
  const float* twW2 = (const float*)d_in[22];
  const float* twb2 = (const float*)d_in[23];
  const float* twW3 = (const float*)d_in[24];
  const float* twb3 = (const float*)d_in[25];

  u16* pkw = (u16*)d_ws;          // needs 819200 B
  float* outp = (float*)d_out;

  prep_pack<<<(NPACK + 255)/256, 256, 0, stream>>>(eW1, eW2, eW3, tgW1, twW1, twW2, fgA, fgB, pkw);
  home_main<<<65536/32, 256, 0, stream>>>(zs, zg0, zg1, tgW2, tgb1, tgb2,
      eb1, eb2, eb3, lns, lnb, sgW, sgb, twb1, twb2, twW3, twb3,
      pkw, outp);
}